// Round 2
// 4946.788 us; speedup vs baseline: 1.0091x; 1.0091x over previous
//
#include <hip/hip_runtime.h>
#include <math.h>

#define Bc 8
#define Sc 4096
#define HIDc 1280
#define CROSSc 768
#define HEADSc 20
#define HDIMc 64
#define ETOKc 113
#define Mc (Bc * Sc) /* 32768 */
#define CHUNKR 4096
#define NCHUNK 8
#define QRN 2560
#define QRK 3840
#define MAXFLAG 4096

typedef unsigned short u16;
typedef __attribute__((ext_vector_type(8))) short bf16x8;
typedef __attribute__((ext_vector_type(4))) float f32x4;

__device__ __forceinline__ float b2f(u16 u) {
  union { unsigned int i; float f; } x; x.i = ((unsigned int)u) << 16; return x.f;
}
__device__ __forceinline__ u16 f2b(float f) {
  union { float f; unsigned int i; } x; x.f = f;
  unsigned int r = x.i + 0x7FFFu + ((x.i >> 16) & 1u);
  return (u16)(r >> 16);
}
__device__ __forceinline__ float gelu_exact(float x) {
  return 0.5f * x * (1.0f + erff(x * 0.70710678118654752440f));
}

// ---------------------------------------------------------------------------
// Shared GEMM building blocks: 128x128 tile, BK=64 bf16, 256 threads (4 waves
// in 2x2), each wave 4x4 grid of 16x16x32 MFMAs. A (MxK,lda) row-major, W
// (NxK,ldw) row-major (i.e. B^T). LDS tiles row-major 64 bf16/row, no padding
// (global_load_lds needs lane-contiguous LDS: base + lane*16).
// ---------------------------------------------------------------------------
__device__ __forceinline__ void stage_tiles(
    const u16* __restrict__ A, int lda, int M, int r0,
    const u16* __restrict__ W, int ldw, int N, int c0,
    int k0, u16* smA, u16* smB, int wv, int lane) {
  const int srow = lane >> 3;         // 0..7
  const int scol = (lane & 7) * 8;    // k elem offset
#pragma unroll
  for (int ci = 0; ci < 4; ci++) {
    int c = wv + ci * 4;              // chunk 0..15, wave-uniform
    int ar = r0 + c * 8 + srow; ar = ar < M ? ar : M - 1;
    const u16* ga = A + (size_t)ar * lda + k0 + scol;
    __builtin_amdgcn_global_load_lds((const __attribute__((address_space(1))) void*)ga,
                                     (__attribute__((address_space(3))) void*)(smA + c * 512), 16, 0, 0);
    int br = c0 + c * 8 + srow; br = br < N ? br : N - 1;
    const u16* gb = W + (size_t)br * ldw + k0 + scol;
    __builtin_amdgcn_global_load_lds((const __attribute__((address_space(1))) void*)gb,
                                     (__attribute__((address_space(3))) void*)(smB + c * 512), 16, 0, 0);
  }
}

__device__ __forceinline__ void mfma_tiles(const u16* smA, const u16* smB,
                                           int wr, int wc, int lane, f32x4 acc[4][4]) {
#pragma unroll
  for (int kh = 0; kh < 2; kh++) {
    const int ko = kh * 32 + (lane >> 4) * 8;  // A[m=lane&15][k=quad*8+j]
    bf16x8 af[4], bfv[4];
#pragma unroll
    for (int i = 0; i < 4; i++)
      af[i] = *(const bf16x8*)(smA + (wr * 64 + i * 16 + (lane & 15)) * 64 + ko);
#pragma unroll
    for (int j = 0; j < 4; j++)
      bfv[j] = *(const bf16x8*)(smB + (wc * 64 + j * 16 + (lane & 15)) * 64 + ko);
#pragma unroll
    for (int i = 0; i < 4; i++)
#pragma unroll
      for (int j = 0; j < 4; j++)
        acc[i][j] = __builtin_amdgcn_mfma_f32_16x16x32_bf16(af[i], bfv[j], acc[i][j], 0, 0, 0);
  }
}

// CMODE 0: fp32 out (add fp32); CMODE 1: bf16 out (add bf16).
template <int CMODE>
__global__ __launch_bounds__(256) void gemm_bf16(
    const u16* __restrict__ A, int lda, const u16* __restrict__ W, int ldw,
    int M, int N, int K, float alpha, const float* __restrict__ bias,
    const void* __restrict__ addp, void* __restrict__ Cp) {
  __shared__ __align__(16) u16 smA[128 * 64];
  __shared__ __align__(16) u16 smB[128 * 64];
  const int t = threadIdx.x, lane = t & 63, wv = t >> 6;
  const int wr = wv >> 1, wc = wv & 1;
  const int r0 = blockIdx.y * 128, c0 = blockIdx.x * 128;
  f32x4 acc[4][4] = {};
  for (int k0 = 0; k0 < K; k0 += 64) {
    stage_tiles(A, lda, M, r0, W, ldw, N, c0, k0, smA, smB, wv, lane);
    __syncthreads();
    mfma_tiles(smA, smB, wr, wc, lane, acc);
    __syncthreads();
  }
  const int cl = lane & 15, quad = lane >> 4;
#pragma unroll
  for (int i = 0; i < 4; i++) {
#pragma unroll
    for (int j = 0; j < 4; j++) {
      int gc = c0 + wc * 64 + j * 16 + cl;
      if (gc >= N) continue;
      float bv = bias ? bias[gc] : 0.0f;
#pragma unroll
      for (int r = 0; r < 4; r++) {
        int gr = r0 + wr * 64 + i * 16 + quad * 4 + r;  // D: col=lane&15, row=quad*4+reg
        if (gr >= M) continue;
        float v = alpha * acc[i][j][r] + bv;
        if (CMODE == 0) {
          const float* add = (const float*)addp;
          if (add) v += add[(size_t)gr * N + gc];
          ((float*)Cp)[(size_t)gr * N + gc] = v;
        } else {
          const u16* add = (const u16*)addp;
          if (add) v += b2f(add[(size_t)gr * N + gc]);
          ((u16*)Cp)[(size_t)gr * N + gc] = f2b(v);
        }
      }
    }
  }
}

// Split-bf16 qr GEMM (K=3840 = hi.hi + hi.lo + lo.hi) with fused
// gelu(t1+b1) . crk epilogue -> atomic partial logits. M=CHUNKR, N=QRN.
__global__ __launch_bounds__(256) void gemm_qr(
    const u16* __restrict__ A, const u16* __restrict__ W,
    const float* __restrict__ b1, const float* __restrict__ crk0,
    const float* __restrict__ crk1, float* __restrict__ LOG, int mbase) {
  __shared__ __align__(16) u16 smA[128 * 64];
  __shared__ __align__(16) u16 smB[128 * 64];
  const int t = threadIdx.x, lane = t & 63, wv = t >> 6;
  const int wr = wv >> 1, wc = wv & 1;
  const int r0 = blockIdx.y * 128, c0 = blockIdx.x * 128;
  f32x4 acc[4][4] = {};
  for (int k0 = 0; k0 < QRK; k0 += 64) {
    stage_tiles(A, QRK, CHUNKR, r0, W, QRK, QRN, c0, k0, smA, smB, wv, lane);
    __syncthreads();
    mfma_tiles(smA, smB, wr, wc, lane, acc);
    __syncthreads();
  }
  const int cl = lane & 15, quad = lane >> 4;
#pragma unroll
  for (int i = 0; i < 4; i++) {
    float p0[4] = {0.f, 0.f, 0.f, 0.f};
    float p1[4] = {0.f, 0.f, 0.f, 0.f};
#pragma unroll
    for (int j = 0; j < 4; j++) {
      int gc = c0 + wc * 64 + j * 16 + cl;
      float bv = b1[gc], c0v = crk0[gc], c1v = crk1[gc];
#pragma unroll
      for (int r = 0; r < 4; r++) {
        float g = gelu_exact(acc[i][j][r] + bv);
        p0[r] = fmaf(g, c0v, p0[r]);
        p1[r] = fmaf(g, c1v, p1[r]);
      }
    }
#pragma unroll
    for (int off = 1; off < 16; off <<= 1) {
#pragma unroll
      for (int r = 0; r < 4; r++) {
        p0[r] += __shfl_xor(p0[r], off);
        p1[r] += __shfl_xor(p1[r], off);
      }
    }
    if (cl == 0) {
#pragma unroll
      for (int r = 0; r < 4; r++) {
        int gm = mbase + r0 + wr * 64 + i * 16 + quad * 4 + r;
        atomicAdd(&LOG[2 * gm + 0], p0[r]);
        atomicAdd(&LOG[2 * gm + 1], p1[r]);
      }
    }
  }
}

// ---------------------------------------------------------------------------
// Casts
// ---------------------------------------------------------------------------
__global__ void cast_bf16_kernel(const float* __restrict__ src, u16* __restrict__ dst, int n4) {
  int i = blockIdx.x * 256 + threadIdx.x;
  if (i >= n4) return;
  float4 v = ((const float4*)src)[i];
  ushort4 o;
  o.x = f2b(v.x); o.y = f2b(v.y); o.z = f2b(v.z); o.w = f2b(v.w);
  ((ushort4*)dst)[i] = o;
}

__global__ void castX_chunk_kernel(const float* __restrict__ X, u16* __restrict__ Xb,
                                   u16* __restrict__ Xcat, int rowstart) {
  int i = blockIdx.x * 256 + threadIdx.x;
  if (i >= CHUNKR * HIDc) return;
  int r = i / HIDc, c = i % HIDc;
  float x = X[(size_t)(rowstart + r) * HIDc + c];
  u16 hi = f2b(x);
  u16 lob = f2b(x - b2f(hi));
  Xb[(size_t)(rowstart + r) * HIDc + c] = hi;
  size_t rb = (size_t)r * QRK;
  Xcat[rb + c] = hi; Xcat[rb + HIDc + c] = hi; Xcat[rb + 2 * HIDc + c] = lob;
}

__global__ void cast_w1_kernel(const float* __restrict__ w1, u16* __restrict__ W1cat) {
  int i = blockIdx.x * 256 + threadIdx.x;
  if (i >= QRN * HIDc) return;
  int r = i / HIDc, c = i % HIDc;
  float w = w1[i];
  u16 hi = f2b(w);
  u16 lob = f2b(w - b2f(hi));
  size_t rb = (size_t)r * QRK;
  W1cat[rb + c] = hi; W1cat[rb + HIDc + c] = lob; W1cat[rb + 2 * HIDc + c] = hi;
}

__global__ void slice_kernel(const float* __restrict__ E, u16* __restrict__ txt,
                             u16* __restrict__ ip, u16* __restrict__ fid) {
  int i = blockIdx.x * 256 + threadIdx.x;
  if (i >= Bc * ETOKc * CROSSc) return;
  int c = i % CROSSc;
  int rr = i / CROSSc;
  int tok = rr % ETOKc, b = rr / ETOKc;
  u16 v = f2b(E[i]);
  if (tok < 77) txt[((size_t)b * 77 + tok) * CROSSc + c] = v;
  else if (tok < 81) ip[((size_t)b * 4 + (tok - 77)) * CROSSc + c] = v;
  else fid[((size_t)b * 32 + (tok - 81)) * CROSSc + c] = v;
}

// ---------------------------------------------------------------------------
// Routing-key chain (tiny, fp32, unchanged) + tau
// ---------------------------------------------------------------------------
__global__ void ragg_kernel(const float* __restrict__ E, const float* __restrict__ aw,
                            const float* __restrict__ ab, float* __restrict__ ragg) {
  int i = blockIdx.x * 256 + threadIdx.x;
  if (i >= Bc * 2 * CROSSc) return;
  int c = i % CROSSc;
  int f = (i / CROSSc) & 1;
  int b = i / (2 * CROSSc);
  const float* base = E + ((size_t)b * ETOKc + 81 + f * 16) * CROSSc + c;
  float s = ab[0];
#pragma unroll
  for (int tk = 0; tk < 16; tk++) s = fmaf(base[tk * CROSSc], aw[tk], s);
  ragg[i] = s;
}

__global__ void kr1_kernel(const float* __restrict__ ragg, const float* __restrict__ w1,
                           const float* __restrict__ b1, float* __restrict__ kr1) {
  int i = blockIdx.x * 256 + threadIdx.x;
  if (i >= 16 * 1536) return;
  int j = i % 1536, bf = i / 1536;
  const float* a = ragg + (size_t)bf * CROSSc;
  const float* w = w1 + (size_t)j * CROSSc;
  float s = b1[j];
  for (int c = 0; c < CROSSc; c++) s = fmaf(a[c], w[c], s);
  kr1[i] = gelu_exact(s);
}

__global__ void rk_kernel(const float* __restrict__ kr1, const float* __restrict__ w2,
                          float* __restrict__ rk) {
  int i = blockIdx.x * 256 + threadIdx.x;
  if (i >= 16 * HIDc) return;
  int d = i % HIDc, bf = i / HIDc;
  const float* a = kr1 + (size_t)bf * 1536;
  const float* w = w2 + (size_t)d * 1536;
  float s = 0.f;
  for (int j = 0; j < 1536; j++) s = fmaf(a[j], w[j], s);
  rk[i] = s;
}

__global__ void crk_kernel(const float* __restrict__ rk, const float* __restrict__ qr_w2,
                           float* __restrict__ crk) {
  int i = blockIdx.x * 256 + threadIdx.x;
  if (i >= 16 * QRN) return;
  int e = i % QRN, bf = i / QRN;
  const float* r = rk + (size_t)bf * HIDc;
  float s = 0.f;
  for (int d = 0; d < HIDc; d++) s = fmaf(r[d], qr_w2[(size_t)d * QRN + e], s);
  crk[i] = s;
}

__global__ void tau_kernel(const float* __restrict__ crk, float* __restrict__ tau) {
  __shared__ float red[256];
  int t = threadIdx.x, b = blockIdx.x;
  const float* c0 = crk + (size_t)(b * 2) * QRN;
  const float* c1 = c0 + QRN;
  float s = 0.f;
  for (int e = t; e < QRN; e += 256) { float d = c0[e] - c1[e]; s = fmaf(d, d, s); }
  red[t] = s; __syncthreads();
  for (int o = 128; o; o >>= 1) { if (t < o) red[t] += red[t + o]; __syncthreads(); }
  if (t == 0) tau[b] = 1e-4f * sqrtf(red[0]);  // ~22x split-bf16 err rms
}

__global__ void route_flag_kernel(const float* __restrict__ LOG, const float* __restrict__ tau,
                                  int* __restrict__ route, int* __restrict__ flags,
                                  int* __restrict__ count) {
  int i = blockIdx.x * 256 + threadIdx.x;
  if (i >= Mc) return;
  float l0 = LOG[2 * i], l1 = LOG[2 * i + 1];
  route[i] = (l1 > l0) ? 1 : 0;
  if (fabsf(l1 - l0) < tau[i >> 12]) {
    int idx = atomicAdd(count, 1);
    if (idx < MAXFLAG) flags[idx] = i;
  }
}

// Exact fp32 recompute of routing for near-tie rows.
__global__ __launch_bounds__(256) void fixup_kernel(
    const float* __restrict__ X, const float* __restrict__ w1,
    const float* __restrict__ b1, const float* __restrict__ crk,
    const int* __restrict__ flags, const int* __restrict__ count,
    int* __restrict__ route) {
  __shared__ float xr[HIDc];
  __shared__ float r0s[4], r1s[4];
  int n = *count; if (n > MAXFLAG) n = MAXFLAG;
  for (int fi = blockIdx.x; fi < n; fi += gridDim.x) {
    int m = flags[fi];
    int b = m >> 12;
    __syncthreads();
    for (int k = threadIdx.x; k < HIDc; k += 256) xr[k] = X[(size_t)m * HIDc + k];
    __syncthreads();
    float p0 = 0.f, p1 = 0.f;
    for (int e = threadIdx.x; e < QRN; e += 256) {
      const float* w = w1 + (size_t)e * HIDc;
      float s = b1[e];
      for (int k = 0; k < HIDc; k++) s = fmaf(xr[k], w[k], s);
      float g = gelu_exact(s);
      p0 = fmaf(g, crk[(size_t)(b * 2) * QRN + e], p0);
      p1 = fmaf(g, crk[(size_t)(b * 2 + 1) * QRN + e], p1);
    }
    for (int o = 32; o; o >>= 1) { p0 += __shfl_down(p0, o); p1 += __shfl_down(p1, o); }
    int wvi = threadIdx.x >> 6;
    if ((threadIdx.x & 63) == 0) { r0s[wvi] = p0; r1s[wvi] = p1; }
    __syncthreads();
    if (threadIdx.x == 0)
      route[m] = ((r1s[0] + r1s[1] + r1s[2] + r1s[3]) >
                  (r0s[0] + r0s[1] + r0s[2] + r0s[3])) ? 1 : 0;
    __syncthreads();
  }
}

// ---------------------------------------------------------------------------
// Fused triple attention — lane-pair-split version.
// Each query row is handled by TWO adjacent threads: thread (2i) owns head
// dims 0..31, thread (2i+1) owns dims 32..63. Per-thread live state halves
// (q[8]+hacc[8]+o[8] f32x4 = 96 regs) -> no scratch spill (the previous
// full-row version hit the 256-VGPR cap and spilled ~670 MB/dispatch).
// Half dot-products are combined with one __shfl_xor(d,1) per key; both
// lanes then run identical softmax state (f32 add is commutative -> bit-
// identical). 256 thr/block = 128 rows/block, grid.x = Sc/128.
// ---------------------------------------------------------------------------
__global__ __launch_bounds__(256) void attn_kernel(
    const u16* __restrict__ Q, const float* __restrict__ Kb,
    const float* __restrict__ Vb, const float* __restrict__ IPK,
    const float* __restrict__ IPV, const float* __restrict__ FK,
    const float* __restrict__ FV, const int* __restrict__ route,
    u16* __restrict__ H) {
  __shared__ float lds[226 * 64];
  const int t = threadIdx.x;
  const int b = blockIdx.z, hh = blockIdx.y;
  const int s0 = blockIdx.x * 128;
  for (int idx = t; idx < 226 * 16; idx += 256) {
    int row = idx >> 4, c4 = idx & 15;
    const float* src;
    if (row < 77)       src = Kb  + ((size_t)(b * 77 + row)) * HIDc;
    else if (row < 154) src = Vb  + ((size_t)(b * 77 + (row - 77))) * HIDc;
    else if (row < 158) src = IPK + ((size_t)(b * 4 + (row - 154))) * HIDc;
    else if (row < 162) src = IPV + ((size_t)(b * 4 + (row - 158))) * HIDc;
    else if (row < 194) src = FK  + ((size_t)(b * 32 + (row - 162))) * HIDc;
    else                src = FV  + ((size_t)(b * 32 + (row - 194))) * HIDc;
    ((float4*)lds)[idx] = ((const float4*)(src + hh * HDIMc))[c4];
  }
  __syncthreads();
  const int r = t >> 1;    // row within block (0..127)
  const int hf = t & 1;    // which 32-dim half this lane owns
  const size_t m = (size_t)b * Sc + s0 + r;
  const u16* qp = Q + m * HIDc + hh * HDIMc + hf * 32;
  // load 32 bf16 q values as 4x16B, unpack to 8 float4
  float4 q[8];
#pragma unroll
  for (int i = 0; i < 4; i++) {
    uint4 u = ((const uint4*)qp)[i];
    union { unsigned int w; struct { u16 lo, hi; } h; } a, bb, c, d;
    a.w = u.x; bb.w = u.y; c.w = u.z; d.w = u.w;
    q[2 * i + 0] = make_float4(b2f(a.h.lo), b2f(a.h.hi), b2f(bb.h.lo), b2f(bb.h.hi));
    q[2 * i + 1] = make_float4(b2f(c.h.lo), b2f(c.h.hi), b2f(d.h.lo), b2f(d.h.hi));
  }
  float4 hacc[8] = {};
  const int face = route[m];

  auto segment = [&](int koff, int voff, int nk, float coef) {
    float mx = -1e30f, l = 0.0f;
    float4 o[8] = {};
    for (int k = 0; k < nk; k++) {
      const float4* kr = (const float4*)(lds + (koff + k) * 64 + hf * 32);
      float d0 = 0.f, d1 = 0.f, d2 = 0.f, d3 = 0.f;
#pragma unroll
      for (int i = 0; i < 8; i++) {
        float4 kk = kr[i];
        d0 = fmaf(q[i].x, kk.x, d0);
        d1 = fmaf(q[i].y, kk.y, d1);
        d2 = fmaf(q[i].z, kk.z, d2);
        d3 = fmaf(q[i].w, kk.w, d3);
      }
      float d = (d0 + d1) + (d2 + d3);
      d += __shfl_xor(d, 1);           // combine the two 32-dim halves
      d *= 0.125f;
      float nm = fmaxf(mx, d);
      float corr = __expf(mx - nm);
      float w = __expf(d - nm);
      l = l * corr + w;
      const float4* vr = (const float4*)(lds + (voff + k) * 64 + hf * 32);
#pragma unroll
      for (int i = 0; i < 8; i++) {
        float4 vv = vr[i];
        o[i].x = fmaf(w, vv.x, o[i].x * corr);
        o[i].y = fmaf(w, vv.y, o[i].y * corr);
        o[i].z = fmaf(w, vv.z, o[i].z * corr);
        o[i].w = fmaf(w, vv.w, o[i].w * corr);
      }
      mx = nm;
    }
    float inv = coef / l;
#pragma unroll
    for (int i = 0; i < 8; i++) {
      hacc[i].x = fmaf(o[i].x, inv, hacc[i].x);
      hacc[i].y = fmaf(o[i].y, inv, hacc[i].y);
      hacc[i].z = fmaf(o[i].z, inv, hacc[i].z);
      hacc[i].w = fmaf(o[i].w, inv, hacc[i].w);
    }
  };
  segment(0, 77, 77, 1.0f);
  segment(154, 158, 4, 0.6f);
  segment(162 + face * 16, 194 + face * 16, 16, 0.7f);

  u16* hp = H + m * HIDc + hh * HDIMc + hf * 32;
#pragma unroll
  for (int i = 0; i < 4; i++) {
    uint4 u;
    u.x = ((unsigned int)f2b(hacc[2 * i].y) << 16) | f2b(hacc[2 * i].x);
    u.y = ((unsigned int)f2b(hacc[2 * i].w) << 16) | f2b(hacc[2 * i].z);
    u.z = ((unsigned int)f2b(hacc[2 * i + 1].y) << 16) | f2b(hacc[2 * i + 1].x);
    u.w = ((unsigned int)f2b(hacc[2 * i + 1].w) << 16) | f2b(hacc[2 * i + 1].z);
    ((uint4*)hp)[i] = u;
  }
}

// ---------------------------------------------------------------------------
extern "C" void kernel_launch(void* const* d_in, const int* in_sizes, int n_in,
                              void* d_out, int out_size, void* d_ws, size_t ws_size,
                              hipStream_t stream) {
  (void)in_sizes; (void)n_in; (void)out_size; (void)ws_size;
  const float* X      = (const float*)d_in[0];
  const float* E      = (const float*)d_in[1];
  const float* wq     = (const float*)d_in[2];
  const float* wk     = (const float*)d_in[3];
  const float* wv     = (const float*)d_in[4];
  const float* wo     = (const float*)d_in[5];
  const float* bo     = (const float*)d_in[6];
  const float* q_ld   = (const float*)d_in[7];
  const float* q_lu   = (const float*)d_in[8];
  const float* k_ld   = (const float*)d_in[9];
  const float* k_lu   = (const float*)d_in[10];
  const float* v_ld   = (const float*)d_in[11];
  const float* v_lu   = (const float*)d_in[12];
  const float* o_ld   = (const float*)d_in[13];
  const float* o_lu   = (const float*)d_in[14];
  const float* wk_ip  = (const float*)d_in[15];
  const float* wv_ip  = (const float*)d_in[16];
  const float* wk_fid = (const float*)d_in[17];
  const float* wv_fid = (const float*)d_in[18];
  const float* qr_w1  = (const float*)d_in[19];
  const float* qr_b1  = (const float*)d_in[20];
  const float* qr_w2  = (const float*)d_in[21];
  const float* kr_w1  = (const float*)d_in[22];
  const float* kr_b1  = (const float*)d_in[23];
  const float* kr_w2  = (const float*)d_in[24];
  const float* aggr_w = (const float*)d_in[25];
  const float* aggr_b = (const float*)d_in[26];
  float* out = (float*)d_out;

  char* base = (char*)d_ws;
  size_t off = 0;
  auto alloc = [&](size_t bytes) -> void* {
    off = (off + 255) & ~(size_t)255;
    void* p = base + off; off += bytes; return p;
  };
  u16* Xb    = (u16*)alloc((size_t)Mc * HIDc * 2);
  u16* Xcat  = (u16*)alloc((size_t)CHUNKR * QRK * 2);
  u16* W1cat = (u16*)alloc((size_t)QRN * QRK * 2);
  u16* Qb    = (u16*)alloc((size_t)Mc * HIDc * 2);
  u16* Hb    = (u16*)alloc((size_t)Mc * HIDc * 2);
  u16* TMPb  = (u16*)alloc((size_t)Mc * 128 * 2);
  u16* TMPo  = (u16*)alloc((size_t)Mc * 128 * 2);
  float* Kb  = (float*)alloc((size_t)Bc * 77 * HIDc * 4);
  float* Vb  = (float*)alloc((size_t)Bc * 77 * HIDc * 4);
  float* IPK = (float*)alloc((size_t)Bc * 4 * HIDc * 4);
  float* IPV = (float*)alloc((size_t)Bc * 4 * HIDc * 4);
  float* FK  = (float*)alloc((size_t)Bc * 32 * HIDc * 4);
  float* FV  = (float*)alloc((size_t)Bc * 32 * HIDc * 4);
  u16* TXTb  = (u16*)alloc((size_t)Bc * 77 * CROSSc * 2);
  u16* IPCb  = (u16*)alloc((size_t)Bc * 4 * CROSSc * 2);
  u16* FIDCb = (u16*)alloc((size_t)Bc * 32 * CROSSc * 2);
  u16* TTb   = (u16*)alloc((size_t)Bc * 77 * 128 * 2);
  u16* wqb   = (u16*)alloc((size_t)HIDc * HIDc * 2);
  u16* wob   = (u16*)alloc((size_t)HIDc * HIDc * 2);
  u16* wkb   = (u16*)alloc((size_t)HIDc * CROSSc * 2);
  u16* wvb   = (u16*)alloc((size_t)HIDc * CROSSc * 2);
  u16* wkipb = (u16*)alloc((size_t)HIDc * CROSSc * 2);
  u16* wvipb = (u16*)alloc((size_t)HIDc * CROSSc * 2);
  u16* wkfb  = (u16*)alloc((size_t)HIDc * CROSSc * 2);
  u16* wvfb  = (u16*)alloc((size_t)HIDc * CROSSc * 2);
  u16* qldb  = (u16*)alloc((size_t)128 * HIDc * 2);
  u16* qlub  = (u16*)alloc((size_t)HIDc * 128 * 2);
  u16* kldb  = (u16*)alloc((size_t)128 * CROSSc * 2);
  u16* klub  = (u16*)alloc((size_t)HIDc * 128 * 2);
  u16* vldb  = (u16*)alloc((size_t)128 * CROSSc * 2);
  u16* vlub  = (u16*)alloc((size_t)HIDc * 128 * 2);
  u16* oldb  = (u16*)alloc((size_t)128 * HIDc * 2);
  u16* olub  = (u16*)alloc((size_t)HIDc * 128 * 2);
  float* RAGG = (float*)alloc(16 * CROSSc * 4);
  float* KR1  = (float*)alloc(16 * 1536 * 4);
  float* RK   = (float*)alloc(16 * HIDc * 4);
  float* CRK  = (float*)alloc(16 * QRN * 4);
  float* TAU  = (float*)alloc(Bc * 4);
  float* LOG  = (float*)alloc((size_t)Mc * 2 * 4);
  int* ROUTE  = (int*)alloc((size_t)Mc * 4);
  int* FLAGS  = (int*)alloc(MAXFLAG * 4);
  int* COUNT  = (int*)alloc(4);

  auto castW = [&](const float* s, u16* d, int n) {
    cast_bf16_kernel<<<(n / 4 + 255) / 256, 256, 0, stream>>>(s, d, n / 4);
  };
  auto G0 = [&](const u16* A, int lda, const u16* W, int ldw, int M, int N, int K,
                float alpha, const float* bias, const float* add, float* C) {
    gemm_bf16<0><<<dim3(N / 128, (M + 127) / 128), 256, 0, stream>>>(
        A, lda, W, ldw, M, N, K, alpha, bias, (const void*)add, (void*)C);
  };
  auto G1 = [&](const u16* A, int lda, const u16* W, int ldw, int M, int N, int K,
                float alpha, const u16* add, u16* C) {
    gemm_bf16<1><<<dim3(N / 128, (M + 127) / 128), 256, 0, stream>>>(
        A, lda, W, ldw, M, N, K, alpha, nullptr, (const void*)add, (void*)C);
  };

  // --- slices + routing-key chain + tau ---
  slice_kernel<<<(Bc * ETOKc * CROSSc + 255) / 256, 256, 0, stream>>>(E, TXTb, IPCb, FIDCb);
  ragg_kernel<<<(Bc * 2 * CROSSc + 255) / 256, 256, 0, stream>>>(E, aggr_w, aggr_b, RAGG);
  kr1_kernel<<<(16 * 1536 + 255) / 256, 256, 0, stream>>>(RAGG, kr_w1, kr_b1, KR1);
  rk_kernel<<<(16 * HIDc + 255) / 256, 256, 0, stream>>>(KR1, kr_w2, RK);
  crk_kernel<<<(16 * QRN + 255) / 256, 256, 0, stream>>>(RK, qr_w2, CRK);
  tau_kernel<<<Bc, 256, 0, stream>>>(CRK, TAU);

  // --- weight casts ---
  castW(wq, wqb, HIDc * HIDc);     castW(wo, wob, HIDc * HIDc);
  castW(wk, wkb, HIDc * CROSSc);   castW(wv, wvb, HIDc * CROSSc);
  castW(wk_ip, wkipb, HIDc * CROSSc); castW(wv_ip, wvipb, HIDc * CROSSc);
  castW(wk_fid, wkfb, HIDc * CROSSc); castW(wv_fid, wvfb, HIDc * CROSSc);
  castW(q_ld, qldb, 128 * HIDc);   castW(q_lu, qlub, HIDc * 128);
  castW(k_ld, kldb, 128 * CROSSc); castW(k_lu, klub, HIDc * 128);
  castW(v_ld, vldb, 128 * CROSSc); castW(v_lu, vlub, HIDc * 128);
  castW(o_ld, oldb, 128 * HIDc);   castW(o_lu, olub, HIDc * 128);
  cast_w1_kernel<<<(QRN * HIDc + 255) / 256, 256, 0, stream>>>(qr_w1, W1cat);

  // --- split-bf16 qr MLP -> logits (chunked over M; chunk == batch) ---
  hipMemsetAsync(LOG, 0, (size_t)Mc * 2 * 4, stream);
  hipMemsetAsync(COUNT, 0, 4, stream);
  for (int ch = 0; ch < NCHUNK; ch++) {
    castX_chunk_kernel<<<(CHUNKR * HIDc + 255) / 256, 256, 0, stream>>>(X, Xb, Xcat, ch * CHUNKR);
    gemm_qr<<<dim3(QRN / 128, CHUNKR / 128), 256, 0, stream>>>(
        Xcat, W1cat, qr_b1, CRK + (size_t)(ch * 2) * QRN, CRK + (size_t)(ch * 2 + 1) * QRN,
        LOG, ch * CHUNKR);
  }
  route_flag_kernel<<<(Mc + 255) / 256, 256, 0, stream>>>(LOG, TAU, ROUTE, FLAGS, COUNT);
  fixup_kernel<<<64, 256, 0, stream>>>(X, qr_w1, qr_b1, CRK, FLAGS, COUNT, ROUTE);

  // --- query projection + LoRA (bf16 MFMA) ---
  G1(Xb, HIDc, qldb, HIDc, Mc, 128, HIDc, 1.0f, nullptr, TMPb);
  G1(Xb, HIDc, wqb, HIDc, Mc, HIDc, HIDc, 1.0f, nullptr, Qb);
  G1(TMPb, 128, qlub, 128, Mc, HIDc, 128, 0.6f, Qb, Qb);

  // --- text K/V + LoRA ---
  const int Mt = Bc * 77;
  G0(TXTb, CROSSc, wkb, CROSSc, Mt, HIDc, CROSSc, 1.0f, nullptr, nullptr, Kb);
  G1(TXTb, CROSSc, kldb, CROSSc, Mt, 128, CROSSc, 1.0f, nullptr, TTb);
  G0(TTb, 128, klub, 128, Mt, HIDc, 128, 0.6f, nullptr, Kb, Kb);
  G0(TXTb, CROSSc, wvb, CROSSc, Mt, HIDc, CROSSc, 1.0f, nullptr, nullptr, Vb);
  G1(TXTb, CROSSc, vldb, CROSSc, Mt, 128, CROSSc, 1.0f, nullptr, TTb);
  G0(TTb, 128, vlub, 128, Mt, HIDc, 128, 0.6f, nullptr, Vb, Vb);

  // --- ip / fid K,V ---
  G0(IPCb, CROSSc, wkipb, CROSSc, Bc * 4, HIDc, CROSSc, 1.0f, nullptr, nullptr, IPK);
  G0(IPCb, CROSSc, wvipb, CROSSc, Bc * 4, HIDc, CROSSc, 1.0f, nullptr, nullptr, IPV);
  G0(FIDCb, CROSSc, wkfb, CROSSc, Bc * 32, HIDc, CROSSc, 1.0f, nullptr, nullptr, FK);
  G0(FIDCb, CROSSc, wvfb, CROSSc, Bc * 32, HIDc, CROSSc, 1.0f, nullptr, nullptr, FV);

  // --- fused triple attention (lane-pair split, 128 rows/block) ---
  attn_kernel<<<dim3(Sc / 128, HEADSc, Bc), 256, 0, stream>>>(Qb, Kb, Vb, IPK, IPV, FK, FV, ROUTE, Hb);

  // --- output projection + LoRA + bias + residual ---
  G1(Hb, HIDc, oldb, HIDc, Mc, 128, HIDc, 1.0f, nullptr, TMPo);
  G0(TMPo, 128, olub, 128, Mc, HIDc, 128, 0.6f, bo, X, out);
  G0(Hb, HIDc, wob, HIDc, Mc, HIDc, HIDc, 1.0f, nullptr, out, out);
}

// Round 4
// 4271.591 us; speedup vs baseline: 1.1686x; 1.1581x over previous
//
#include <hip/hip_runtime.h>
#include <math.h>

#define Bc 8
#define Sc 4096
#define HIDc 1280
#define CROSSc 768
#define HEADSc 20
#define HDIMc 64
#define ETOKc 113
#define Mc (Bc * Sc) /* 32768 */
#define CHUNKR 4096
#define NCHUNK 8
#define QRN 2560
#define QRK 3840
#define MAXFLAG 4096

typedef unsigned short u16;
typedef __attribute__((ext_vector_type(8))) short bf16x8;
typedef __attribute__((ext_vector_type(4))) float f32x4;

__device__ __forceinline__ float b2f(u16 u) {
  union { unsigned int i; float f; } x; x.i = ((unsigned int)u) << 16; return x.f;
}
__device__ __forceinline__ u16 f2b(float f) {
  union { float f; unsigned int i; } x; x.f = f;
  unsigned int r = x.i + 0x7FFFu + ((x.i >> 16) & 1u);
  return (u16)(r >> 16);
}
__device__ __forceinline__ float gelu_exact(float x) {
  return 0.5f * x * (1.0f + erff(x * 0.70710678118654752440f));
}

// ---------------------------------------------------------------------------
// Shared GEMM building blocks: 128x128 tile, BK=64 bf16, 256 threads (4 waves
// in 2x2), each wave 4x4 grid of 16x16x32 MFMAs. A (MxK,lda) row-major, W
// (NxK,ldw) row-major (i.e. B^T). LDS tiles row-major 64 bf16/row, no padding
// (global_load_lds needs lane-contiguous LDS: base + lane*16).
// ---------------------------------------------------------------------------
__device__ __forceinline__ void stage_tiles(
    const u16* __restrict__ A, int lda, int M, int r0,
    const u16* __restrict__ W, int ldw, int N, int c0,
    int k0, u16* smA, u16* smB, int wv, int lane) {
  const int srow = lane >> 3;         // 0..7
  const int scol = (lane & 7) * 8;    // k elem offset
#pragma unroll
  for (int ci = 0; ci < 4; ci++) {
    int c = wv + ci * 4;              // chunk 0..15, wave-uniform
    int ar = r0 + c * 8 + srow; ar = ar < M ? ar : M - 1;
    const u16* ga = A + (size_t)ar * lda + k0 + scol;
    __builtin_amdgcn_global_load_lds((const __attribute__((address_space(1))) void*)ga,
                                     (__attribute__((address_space(3))) void*)(smA + c * 512), 16, 0, 0);
    int br = c0 + c * 8 + srow; br = br < N ? br : N - 1;
    const u16* gb = W + (size_t)br * ldw + k0 + scol;
    __builtin_amdgcn_global_load_lds((const __attribute__((address_space(1))) void*)gb,
                                     (__attribute__((address_space(3))) void*)(smB + c * 512), 16, 0, 0);
  }
}

__device__ __forceinline__ void mfma_tiles(const u16* smA, const u16* smB,
                                           int wr, int wc, int lane, f32x4 acc[4][4]) {
#pragma unroll
  for (int kh = 0; kh < 2; kh++) {
    const int ko = kh * 32 + (lane >> 4) * 8;  // A[m=lane&15][k=quad*8+j]
    bf16x8 af[4], bfv[4];
#pragma unroll
    for (int i = 0; i < 4; i++)
      af[i] = *(const bf16x8*)(smA + (wr * 64 + i * 16 + (lane & 15)) * 64 + ko);
#pragma unroll
    for (int j = 0; j < 4; j++)
      bfv[j] = *(const bf16x8*)(smB + (wc * 64 + j * 16 + (lane & 15)) * 64 + ko);
#pragma unroll
    for (int i = 0; i < 4; i++)
#pragma unroll
      for (int j = 0; j < 4; j++)
        acc[i][j] = __builtin_amdgcn_mfma_f32_16x16x32_bf16(af[i], bfv[j], acc[i][j], 0, 0, 0);
  }
}

// CMODE 0: fp32 out (add fp32); CMODE 1: bf16 out (add bf16).
template <int CMODE>
__global__ __launch_bounds__(256) void gemm_bf16(
    const u16* __restrict__ A, int lda, const u16* __restrict__ W, int ldw,
    int M, int N, int K, float alpha, const float* __restrict__ bias,
    const void* __restrict__ addp, void* __restrict__ Cp) {
  __shared__ __align__(16) u16 smA[128 * 64];
  __shared__ __align__(16) u16 smB[128 * 64];
  const int t = threadIdx.x, lane = t & 63, wv = t >> 6;
  const int wr = wv >> 1, wc = wv & 1;
  const int r0 = blockIdx.y * 128, c0 = blockIdx.x * 128;
  f32x4 acc[4][4] = {};
  for (int k0 = 0; k0 < K; k0 += 64) {
    stage_tiles(A, lda, M, r0, W, ldw, N, c0, k0, smA, smB, wv, lane);
    __syncthreads();
    mfma_tiles(smA, smB, wr, wc, lane, acc);
    __syncthreads();
  }
  const int cl = lane & 15, quad = lane >> 4;
#pragma unroll
  for (int i = 0; i < 4; i++) {
#pragma unroll
    for (int j = 0; j < 4; j++) {
      int gc = c0 + wc * 64 + j * 16 + cl;
      if (gc >= N) continue;
      float bv = bias ? bias[gc] : 0.0f;
#pragma unroll
      for (int r = 0; r < 4; r++) {
        int gr = r0 + wr * 64 + i * 16 + quad * 4 + r;  // D: col=lane&15, row=quad*4+reg
        if (gr >= M) continue;
        float v = alpha * acc[i][j][r] + bv;
        if (CMODE == 0) {
          const float* add = (const float*)addp;
          if (add) v += add[(size_t)gr * N + gc];
          ((float*)Cp)[(size_t)gr * N + gc] = v;
        } else {
          const u16* add = (const u16*)addp;
          if (add) v += b2f(add[(size_t)gr * N + gc]);
          ((u16*)Cp)[(size_t)gr * N + gc] = f2b(v);
        }
      }
    }
  }
}

// Split-bf16 qr GEMM (K=3840 = hi.hi + hi.lo + lo.hi) with fused
// gelu(t1+b1) . crk epilogue -> atomic partial logits. M=CHUNKR, N=QRN.
__global__ __launch_bounds__(256) void gemm_qr(
    const u16* __restrict__ A, const u16* __restrict__ W,
    const float* __restrict__ b1, const float* __restrict__ crk0,
    const float* __restrict__ crk1, float* __restrict__ LOG, int mbase) {
  __shared__ __align__(16) u16 smA[128 * 64];
  __shared__ __align__(16) u16 smB[128 * 64];
  const int t = threadIdx.x, lane = t & 63, wv = t >> 6;
  const int wr = wv >> 1, wc = wv & 1;
  const int r0 = blockIdx.y * 128, c0 = blockIdx.x * 128;
  f32x4 acc[4][4] = {};
  for (int k0 = 0; k0 < QRK; k0 += 64) {
    stage_tiles(A, QRK, CHUNKR, r0, W, QRK, QRN, c0, k0, smA, smB, wv, lane);
    __syncthreads();
    mfma_tiles(smA, smB, wr, wc, lane, acc);
    __syncthreads();
  }
  const int cl = lane & 15, quad = lane >> 4;
#pragma unroll
  for (int i = 0; i < 4; i++) {
    float p0[4] = {0.f, 0.f, 0.f, 0.f};
    float p1[4] = {0.f, 0.f, 0.f, 0.f};
#pragma unroll
    for (int j = 0; j < 4; j++) {
      int gc = c0 + wc * 64 + j * 16 + cl;
      float bv = b1[gc], c0v = crk0[gc], c1v = crk1[gc];
#pragma unroll
      for (int r = 0; r < 4; r++) {
        float g = gelu_exact(acc[i][j][r] + bv);
        p0[r] = fmaf(g, c0v, p0[r]);
        p1[r] = fmaf(g, c1v, p1[r]);
      }
    }
#pragma unroll
    for (int off = 1; off < 16; off <<= 1) {
#pragma unroll
      for (int r = 0; r < 4; r++) {
        p0[r] += __shfl_xor(p0[r], off);
        p1[r] += __shfl_xor(p1[r], off);
      }
    }
    if (cl == 0) {
#pragma unroll
      for (int r = 0; r < 4; r++) {
        int gm = mbase + r0 + wr * 64 + i * 16 + quad * 4 + r;
        atomicAdd(&LOG[2 * gm + 0], p0[r]);
        atomicAdd(&LOG[2 * gm + 1], p1[r]);
      }
    }
  }
}

// ---------------------------------------------------------------------------
// Casts
// ---------------------------------------------------------------------------
__global__ void cast_bf16_kernel(const float* __restrict__ src, u16* __restrict__ dst, int n4) {
  int i = blockIdx.x * 256 + threadIdx.x;
  if (i >= n4) return;
  float4 v = ((const float4*)src)[i];
  ushort4 o;
  o.x = f2b(v.x); o.y = f2b(v.y); o.z = f2b(v.z); o.w = f2b(v.w);
  ((ushort4*)dst)[i] = o;
}

__global__ void castX_chunk_kernel(const float* __restrict__ X, u16* __restrict__ Xb,
                                   u16* __restrict__ Xcat, int rowstart) {
  int i = blockIdx.x * 256 + threadIdx.x;
  if (i >= CHUNKR * HIDc) return;
  int r = i / HIDc, c = i % HIDc;
  float x = X[(size_t)(rowstart + r) * HIDc + c];
  u16 hi = f2b(x);
  u16 lob = f2b(x - b2f(hi));
  Xb[(size_t)(rowstart + r) * HIDc + c] = hi;
  size_t rb = (size_t)r * QRK;
  Xcat[rb + c] = hi; Xcat[rb + HIDc + c] = hi; Xcat[rb + 2 * HIDc + c] = lob;
}

__global__ void cast_w1_kernel(const float* __restrict__ w1, u16* __restrict__ W1cat) {
  int i = blockIdx.x * 256 + threadIdx.x;
  if (i >= QRN * HIDc) return;
  int r = i / HIDc, c = i % HIDc;
  float w = w1[i];
  u16 hi = f2b(w);
  u16 lob = f2b(w - b2f(hi));
  size_t rb = (size_t)r * QRK;
  W1cat[rb + c] = hi; W1cat[rb + HIDc + c] = lob; W1cat[rb + 2 * HIDc + c] = hi;
}

__global__ void slice_kernel(const float* __restrict__ E, u16* __restrict__ txt,
                             u16* __restrict__ ip, u16* __restrict__ fid) {
  int i = blockIdx.x * 256 + threadIdx.x;
  if (i >= Bc * ETOKc * CROSSc) return;
  int c = i % CROSSc;
  int rr = i / CROSSc;
  int tok = rr % ETOKc, b = rr / ETOKc;
  u16 v = f2b(E[i]);
  if (tok < 77) txt[((size_t)b * 77 + tok) * CROSSc + c] = v;
  else if (tok < 81) ip[((size_t)b * 4 + (tok - 77)) * CROSSc + c] = v;
  else fid[((size_t)b * 32 + (tok - 81)) * CROSSc + c] = v;
}

// ---------------------------------------------------------------------------
// Routing-key chain (tiny, fp32, unchanged) + tau
// ---------------------------------------------------------------------------
__global__ void ragg_kernel(const float* __restrict__ E, const float* __restrict__ aw,
                            const float* __restrict__ ab, float* __restrict__ ragg) {
  int i = blockIdx.x * 256 + threadIdx.x;
  if (i >= Bc * 2 * CROSSc) return;
  int c = i % CROSSc;
  int f = (i / CROSSc) & 1;
  int b = i / (2 * CROSSc);
  const float* base = E + ((size_t)b * ETOKc + 81 + f * 16) * CROSSc + c;
  float s = ab[0];
#pragma unroll
  for (int tk = 0; tk < 16; tk++) s = fmaf(base[tk * CROSSc], aw[tk], s);
  ragg[i] = s;
}

__global__ void kr1_kernel(const float* __restrict__ ragg, const float* __restrict__ w1,
                           const float* __restrict__ b1, float* __restrict__ kr1) {
  int i = blockIdx.x * 256 + threadIdx.x;
  if (i >= 16 * 1536) return;
  int j = i % 1536, bf = i / 1536;
  const float* a = ragg + (size_t)bf * CROSSc;
  const float* w = w1 + (size_t)j * CROSSc;
  float s = b1[j];
  for (int c = 0; c < CROSSc; c++) s = fmaf(a[c], w[c], s);
  kr1[i] = gelu_exact(s);
}

__global__ void rk_kernel(const float* __restrict__ kr1, const float* __restrict__ w2,
                          float* __restrict__ rk) {
  int i = blockIdx.x * 256 + threadIdx.x;
  if (i >= 16 * HIDc) return;
  int d = i % HIDc, bf = i / HIDc;
  const float* a = kr1 + (size_t)bf * 1536;
  const float* w = w2 + (size_t)d * 1536;
  float s = 0.f;
  for (int j = 0; j < 1536; j++) s = fmaf(a[j], w[j], s);
  rk[i] = s;
}

__global__ void crk_kernel(const float* __restrict__ rk, const float* __restrict__ qr_w2,
                           float* __restrict__ crk) {
  int i = blockIdx.x * 256 + threadIdx.x;
  if (i >= 16 * QRN) return;
  int e = i % QRN, bf = i / QRN;
  const float* r = rk + (size_t)bf * HIDc;
  float s = 0.f;
  for (int d = 0; d < HIDc; d++) s = fmaf(r[d], qr_w2[(size_t)d * QRN + e], s);
  crk[i] = s;
}

__global__ void tau_kernel(const float* __restrict__ crk, float* __restrict__ tau) {
  __shared__ float red[256];
  int t = threadIdx.x, b = blockIdx.x;
  const float* c0 = crk + (size_t)(b * 2) * QRN;
  const float* c1 = c0 + QRN;
  float s = 0.f;
  for (int e = t; e < QRN; e += 256) { float d = c0[e] - c1[e]; s = fmaf(d, d, s); }
  red[t] = s; __syncthreads();
  for (int o = 128; o; o >>= 1) { if (t < o) red[t] += red[t + o]; __syncthreads(); }
  if (t == 0) tau[b] = 1e-4f * sqrtf(red[0]);  // ~22x split-bf16 err rms
}

__global__ void route_flag_kernel(const float* __restrict__ LOG, const float* __restrict__ tau,
                                  int* __restrict__ route, int* __restrict__ flags,
                                  int* __restrict__ count) {
  int i = blockIdx.x * 256 + threadIdx.x;
  if (i >= Mc) return;
  float l0 = LOG[2 * i], l1 = LOG[2 * i + 1];
  route[i] = (l1 > l0) ? 1 : 0;
  if (fabsf(l1 - l0) < tau[i >> 12]) {
    int idx = atomicAdd(count, 1);
    if (idx < MAXFLAG) flags[idx] = i;
  }
}

// Exact fp32 recompute of routing for near-tie rows.
__global__ __launch_bounds__(256) void fixup_kernel(
    const float* __restrict__ X, const float* __restrict__ w1,
    const float* __restrict__ b1, const float* __restrict__ crk,
    const int* __restrict__ flags, const int* __restrict__ count,
    int* __restrict__ route) {
  __shared__ float xr[HIDc];
  __shared__ float r0s[4], r1s[4];
  int n = *count; if (n > MAXFLAG) n = MAXFLAG;
  for (int fi = blockIdx.x; fi < n; fi += gridDim.x) {
    int m = flags[fi];
    int b = m >> 12;
    __syncthreads();
    for (int k = threadIdx.x; k < HIDc; k += 256) xr[k] = X[(size_t)m * HIDc + k];
    __syncthreads();
    float p0 = 0.f, p1 = 0.f;
    for (int e = threadIdx.x; e < QRN; e += 256) {
      const float* w = w1 + (size_t)e * HIDc;
      float s = b1[e];
      for (int k = 0; k < HIDc; k++) s = fmaf(xr[k], w[k], s);
      float g = gelu_exact(s);
      p0 = fmaf(g, crk[(size_t)(b * 2) * QRN + e], p0);
      p1 = fmaf(g, crk[(size_t)(b * 2 + 1) * QRN + e], p1);
    }
    for (int o = 32; o; o >>= 1) { p0 += __shfl_down(p0, o); p1 += __shfl_down(p1, o); }
    int wvi = threadIdx.x >> 6;
    if ((threadIdx.x & 63) == 0) { r0s[wvi] = p0; r1s[wvi] = p1; }
    __syncthreads();
    if (threadIdx.x == 0)
      route[m] = ((r1s[0] + r1s[1] + r1s[2] + r1s[3]) >
                  (r0s[0] + r0s[1] + r0s[2] + r0s[3])) ? 1 : 0;
    __syncthreads();
  }
}

// ---------------------------------------------------------------------------
// Fused triple attention — MFMA flash version.
// Previous scalar version was VALU-issue-bound (inst-count model == measured
// 868 us). Keys for one (b,h) padded into a 128-row tile:
//   0-76 text | 77-79 pad | 80-83 ip | 84-95 pad | 96-111 fid f0 | 112-127 fid f1
// QK^T computed SWAPPED (A=K, B=Q) -> S^T[key][qrow]: softmax over keys is a
// per-lane reduce over 4 regs + shfl_xor(16,32) across quads. Face selection
// is a per-lane cndmask between the mi=6/7 register blocks. Segment coefs
// (1/lt, 0.6/lip, 0.7/lf) folded into P; pad/masked keys get P=0, so ONE PV
// MFMA pass over all 128 keys yields the combined output.
// K_lds XOR-swizzled (^(row&7)<<4) — row-major 128B-stride column reads are a
// 16-way bank conflict otherwise (G4). P/V^T rows padded to 136 u16 (272B =
// 17*16B: aligned for b128, odd 16B-count spreads banks -> 2-way max).
// 4 waves * 32 qrows = 128 rows/block; LDS 68.6KB -> 2 blocks/CU.
// ---------------------------------------------------------------------------
__global__ __launch_bounds__(256) void attn_kernel(
    const u16* __restrict__ Q, const float* __restrict__ Kb,
    const float* __restrict__ Vb, const float* __restrict__ IPK,
    const float* __restrict__ IPV, const float* __restrict__ FK,
    const float* __restrict__ FV, const int* __restrict__ route,
    u16* __restrict__ H) {
  __shared__ __align__(16) u16 K_lds[128 * 64];       // swizzled, 16KB
  __shared__ __align__(16) u16 V_t[64 * 136];         // V^T [dim][key], 17.4KB
  __shared__ __align__(16) u16 P_lds[4 * 32 * 136];   // per-wave P, 34.8KB
  const int t = threadIdx.x, lane = t & 63, wv = t >> 6;
  const int cl = lane & 15, quad = lane >> 4, qr4 = quad * 4;
  const int b = blockIdx.z, hh = blockIdx.y;
  const int s0 = blockIdx.x * 128;

  // ---- stage K (bf16, swizzled) ----
  for (int idx = t; idx < 128 * 16; idx += 256) {
    const int row = idx >> 4, c4 = idx & 15;
    float4 v = make_float4(0.f, 0.f, 0.f, 0.f);
    const float* src = nullptr;
    if (row < 77)                    src = Kb  + ((size_t)(b * 77 + row)) * HIDc;
    else if (row >= 80 && row < 84)  src = IPK + ((size_t)(b * 4 + row - 80)) * HIDc;
    else if (row >= 96)              src = FK  + ((size_t)(b * 32 + row - 96)) * HIDc;
    if (src) v = ((const float4*)(src + hh * HDIMc))[c4];
    unsigned int w0 = ((unsigned int)f2b(v.y) << 16) | f2b(v.x);
    unsigned int w1 = ((unsigned int)f2b(v.w) << 16) | f2b(v.z);
    int byte = (row * 128 + c4 * 8) ^ ((row & 7) << 4);
    *(uint2*)((char*)K_lds + byte) = make_uint2(w0, w1);
  }
  // ---- stage V^T (pad keys written as zero: P=0 * garbage could be NaN) ----
  for (int idx = t; idx < 128 * 16; idx += 256) {
    const int row = idx >> 4, c4 = idx & 15;
    float4 v = make_float4(0.f, 0.f, 0.f, 0.f);
    const float* src = nullptr;
    if (row < 77)                    src = Vb  + ((size_t)(b * 77 + row)) * HIDc;
    else if (row >= 80 && row < 84)  src = IPV + ((size_t)(b * 4 + row - 80)) * HIDc;
    else if (row >= 96)              src = FV  + ((size_t)(b * 32 + row - 96)) * HIDc;
    if (src) v = ((const float4*)(src + hh * HDIMc))[c4];
    V_t[(c4 * 4 + 0) * 136 + row] = f2b(v.x);
    V_t[(c4 * 4 + 1) * 136 + row] = f2b(v.y);
    V_t[(c4 * 4 + 2) * 136 + row] = f2b(v.z);
    V_t[(c4 * 4 + 3) * 136 + row] = f2b(v.w);
  }
  __syncthreads();

  const size_t mbase = (size_t)b * Sc + s0 + wv * 32;
  // Q fragments straight from global (B-operand: n=lane&15 -> qrow, k=quad*8)
  bf16x8 qf[2][2];
#pragma unroll
  for (int ni = 0; ni < 2; ni++)
#pragma unroll
    for (int kk = 0; kk < 2; kk++)
      qf[ni][kk] = *(const bf16x8*)(Q + (mbase + ni * 16 + cl) * HIDc + hh * HDIMc + kk * 32 + quad * 8);
  const int face[2] = { route[mbase + cl], route[mbase + 16 + cl] };

  // ---- QK^T (swapped): acc[mi][ni] = S^T[key=mi*16+qr4+r][qrow=ni*16+cl] ----
  f32x4 acc[8][2] = {};
#pragma unroll
  for (int kk = 0; kk < 2; kk++) {
    bf16x8 af[8];
#pragma unroll
    for (int mi = 0; mi < 8; mi++) {
      const int row = mi * 16 + cl;
      const int byte = (row * 128 + (kk * 32 + quad * 8) * 2) ^ ((row & 7) << 4);
      af[mi] = *(const bf16x8*)((const char*)K_lds + byte);
    }
#pragma unroll
    for (int mi = 0; mi < 8; mi++)
#pragma unroll
      for (int ni = 0; ni < 2; ni++)
        acc[mi][ni] = __builtin_amdgcn_mfma_f32_16x16x32_bf16(af[mi], qf[ni][kk], acc[mi][ni], 0, 0, 0);
  }

  // ---- per-row softmax (3 segments) + P (coef/l folded in) -> LDS ----
  u16* Pw = P_lds + wv * 32 * 136;
  const float NEG = -1e30f;
#pragma unroll
  for (int ni = 0; ni < 2; ni++) {
    float e[8][4];
#pragma unroll
    for (int mi = 0; mi < 8; mi++)
#pragma unroll
      for (int r = 0; r < 4; r++) e[mi][r] = 0.125f * acc[mi][ni][r];
    // masks: mi4 keys 64..79 valid <=76; mi5 keys 80..95 valid quad==0
#pragma unroll
    for (int r = 0; r < 4; r++) {
      e[4][r] = (qr4 + r <= 12) ? e[4][r] : NEG;
      e[5][r] = (quad == 0) ? e[5][r] : NEG;
    }
    // text: mi 0..4
    float mt = NEG;
#pragma unroll
    for (int mi = 0; mi < 5; mi++)
#pragma unroll
      for (int r = 0; r < 4; r++) mt = fmaxf(mt, e[mi][r]);
    mt = fmaxf(mt, __shfl_xor(mt, 16));
    mt = fmaxf(mt, __shfl_xor(mt, 32));
    float lt = 0.f;
#pragma unroll
    for (int mi = 0; mi < 5; mi++)
#pragma unroll
      for (int r = 0; r < 4; r++) { e[mi][r] = __expf(e[mi][r] - mt); lt += e[mi][r]; }
    lt += __shfl_xor(lt, 16); lt += __shfl_xor(lt, 32);
    // ip: mi 5
    float mp = NEG;
#pragma unroll
    for (int r = 0; r < 4; r++) mp = fmaxf(mp, e[5][r]);
    mp = fmaxf(mp, __shfl_xor(mp, 16));
    mp = fmaxf(mp, __shfl_xor(mp, 32));
    float lp = 0.f;
#pragma unroll
    for (int r = 0; r < 4; r++) { e[5][r] = __expf(e[5][r] - mp); lp += e[5][r]; }
    lp += __shfl_xor(lp, 16); lp += __shfl_xor(lp, 32);
    // fid: per-lane face selects mi6 (f0) or mi7 (f1)
    const int f = face[ni];
    float sf[4];
#pragma unroll
    for (int r = 0; r < 4; r++) sf[r] = f ? e[7][r] : e[6][r];
    float mf = NEG;
#pragma unroll
    for (int r = 0; r < 4; r++) mf = fmaxf(mf, sf[r]);
    mf = fmaxf(mf, __shfl_xor(mf, 16));
    mf = fmaxf(mf, __shfl_xor(mf, 32));
    float lf = 0.f;
#pragma unroll
    for (int r = 0; r < 4; r++) { sf[r] = __expf(sf[r] - mf); lf += sf[r]; }
    lf += __shfl_xor(lf, 16); lf += __shfl_xor(lf, 32);
    const float sct = 1.0f / lt, sci = 0.6f / lp, scf = 0.7f / lf;
#pragma unroll
    for (int mi = 0; mi < 5; mi++)
#pragma unroll
      for (int r = 0; r < 4; r++) e[mi][r] *= sct;
#pragma unroll
    for (int r = 0; r < 4; r++) {
      e[5][r] *= sci;
      const float pf = sf[r] * scf;
      e[6][r] = f ? 0.f : pf;
      e[7][r] = f ? pf : 0.f;
    }
    // pack (round-to-nearest bf16) + write 4 keys (8B) per mi
    u16* prow = Pw + (ni * 16 + cl) * 136 + qr4;
#pragma unroll
    for (int mi = 0; mi < 8; mi++) {
      unsigned int a0 = (unsigned int)f2b(e[mi][0]) | ((unsigned int)f2b(e[mi][1]) << 16);
      unsigned int a1 = (unsigned int)f2b(e[mi][2]) | ((unsigned int)f2b(e[mi][3]) << 16);
      *(uint2*)(prow + mi * 16) = make_uint2(a0, a1);
    }
  }

  // ---- PV: out[qrow][dim] = P[qrow][k] * V[k][dim] over all 128 keys ----
  f32x4 pacc[2][4] = {};
#pragma unroll
  for (int kk = 0; kk < 4; kk++) {
    bf16x8 pa[2], vb[4];
#pragma unroll
    for (int mi2 = 0; mi2 < 2; mi2++)
      pa[mi2] = *(const bf16x8*)(Pw + (mi2 * 16 + cl) * 136 + kk * 32 + quad * 8);
#pragma unroll
    for (int ni2 = 0; ni2 < 4; ni2++)
      vb[ni2] = *(const bf16x8*)(V_t + (ni2 * 16 + cl) * 136 + kk * 32 + quad * 8);
#pragma unroll
    for (int mi2 = 0; mi2 < 2; mi2++)
#pragma unroll
      for (int ni2 = 0; ni2 < 4; ni2++)
        pacc[mi2][ni2] = __builtin_amdgcn_mfma_f32_16x16x32_bf16(pa[mi2], vb[ni2], pacc[mi2][ni2], 0, 0, 0);
  }
  // store: D col=lane&15 -> dim, row=quad*4+r -> qrow
#pragma unroll
  for (int mi2 = 0; mi2 < 2; mi2++) {
#pragma unroll
    for (int r = 0; r < 4; r++) {
      u16* hp = H + (mbase + mi2 * 16 + qr4 + r) * HIDc + hh * HDIMc + cl;
#pragma unroll
      for (int ni2 = 0; ni2 < 4; ni2++)
        hp[ni2 * 16] = f2b(pacc[mi2][ni2][r]);
    }
  }
}

// ---------------------------------------------------------------------------
extern "C" void kernel_launch(void* const* d_in, const int* in_sizes, int n_in,
                              void* d_out, int out_size, void* d_ws, size_t ws_size,
                              hipStream_t stream) {
  (void)in_sizes; (void)n_in; (void)out_size; (void)ws_size;
  const float* X      = (const float*)d_in[0];
  const float* E      = (const float*)d_in[1];
  const float* wq     = (const float*)d_in[2];
  const float* wk     = (const float*)d_in[3];
  const float* wv     = (const float*)d_in[4];
  const float* wo     = (const float*)d_in[5];
  const float* bo     = (const float*)d_in[6];
  const float* q_ld   = (const float*)d_in[7];
  const float* q_lu   = (const float*)d_in[8];
  const float* k_ld   = (const float*)d_in[9];
  const float* k_lu   = (const float*)d_in[10];
  const float* v_ld   = (const float*)d_in[11];
  const float* v_lu   = (const float*)d_in[12];
  const float* o_ld   = (const float*)d_in[13];
  const float* o_lu   = (const float*)d_in[14];
  const float* wk_ip  = (const float*)d_in[15];
  const float* wv_ip  = (const float*)d_in[16];
  const float* wk_fid = (const float*)d_in[17];
  const float* wv_fid = (const float*)d_in[18];
  const float* qr_w1  = (const float*)d_in[19];
  const float* qr_b1  = (const float*)d_in[20];
  const float* qr_w2  = (const float*)d_in[21];
  const float* kr_w1  = (const float*)d_in[22];
  const float* kr_b1  = (const float*)d_in[23];
  const float* kr_w2  = (const float*)d_in[24];
  const float* aggr_w = (const float*)d_in[25];
  const float* aggr_b = (const float*)d_in[26];
  float* out = (float*)d_out;

  char* base = (char*)d_ws;
  size_t off = 0;
  auto alloc = [&](size_t bytes) -> void* {
    off = (off + 255) & ~(size_t)255;
    void* p = base + off; off += bytes; return p;
  };
  u16* Xb    = (u16*)alloc((size_t)Mc * HIDc * 2);
  u16* Xcat  = (u16*)alloc((size_t)CHUNKR * QRK * 2);
  u16* W1cat = (u16*)alloc((size_t)QRN * QRK * 2);
  u16* Qb    = (u16*)alloc((size_t)Mc * HIDc * 2);
  u16* Hb    = (u16*)alloc((size_t)Mc * HIDc * 2);
  u16* TMPb  = (u16*)alloc((size_t)Mc * 128 * 2);
  u16* TMPo  = (u16*)alloc((size_t)Mc * 128 * 2);
  float* Kb  = (float*)alloc((size_t)Bc * 77 * HIDc * 4);
  float* Vb  = (float*)alloc((size_t)Bc * 77 * HIDc * 4);
  float* IPK = (float*)alloc((size_t)Bc * 4 * HIDc * 4);
  float* IPV = (float*)alloc((size_t)Bc * 4 * HIDc * 4);
  float* FK  = (float*)alloc((size_t)Bc * 32 * HIDc * 4);
  float* FV  = (float*)alloc((size_t)Bc * 32 * HIDc * 4);
  u16* TXTb  = (u16*)alloc((size_t)Bc * 77 * CROSSc * 2);
  u16* IPCb  = (u16*)alloc((size_t)Bc * 4 * CROSSc * 2);
  u16* FIDCb = (u16*)alloc((size_t)Bc * 32 * CROSSc * 2);
  u16* TTb   = (u16*)alloc((size_t)Bc * 77 * 128 * 2);
  u16* wqb   = (u16*)alloc((size_t)HIDc * HIDc * 2);
  u16* wob   = (u16*)alloc((size_t)HIDc * HIDc * 2);
  u16* wkb   = (u16*)alloc((size_t)HIDc * CROSSc * 2);
  u16* wvb   = (u16*)alloc((size_t)HIDc * CROSSc * 2);
  u16* wkipb = (u16*)alloc((size_t)HIDc * CROSSc * 2);
  u16* wvipb = (u16*)alloc((size_t)HIDc * CROSSc * 2);
  u16* wkfb  = (u16*)alloc((size_t)HIDc * CROSSc * 2);
  u16* wvfb  = (u16*)alloc((size_t)HIDc * CROSSc * 2);
  u16* qldb  = (u16*)alloc((size_t)128 * HIDc * 2);
  u16* qlub  = (u16*)alloc((size_t)HIDc * 128 * 2);
  u16* kldb  = (u16*)alloc((size_t)128 * CROSSc * 2);
  u16* klub  = (u16*)alloc((size_t)HIDc * 128 * 2);
  u16* vldb  = (u16*)alloc((size_t)128 * CROSSc * 2);
  u16* vlub  = (u16*)alloc((size_t)HIDc * 128 * 2);
  u16* oldb  = (u16*)alloc((size_t)128 * HIDc * 2);
  u16* olub  = (u16*)alloc((size_t)HIDc * 128 * 2);
  float* RAGG = (float*)alloc(16 * CROSSc * 4);
  float* KR1  = (float*)alloc(16 * 1536 * 4);
  float* RK   = (float*)alloc(16 * HIDc * 4);
  float* CRK  = (float*)alloc(16 * QRN * 4);
  float* TAU  = (float*)alloc(Bc * 4);
  float* LOG  = (float*)alloc((size_t)Mc * 2 * 4);
  int* ROUTE  = (int*)alloc((size_t)Mc * 4);
  int* FLAGS  = (int*)alloc(MAXFLAG * 4);
  int* COUNT  = (int*)alloc(4);

  auto castW = [&](const float* s, u16* d, int n) {
    cast_bf16_kernel<<<(n / 4 + 255) / 256, 256, 0, stream>>>(s, d, n / 4);
  };
  auto G0 = [&](const u16* A, int lda, const u16* W, int ldw, int M, int N, int K,
                float alpha, const float* bias, const float* add, float* C) {
    gemm_bf16<0><<<dim3(N / 128, (M + 127) / 128), 256, 0, stream>>>(
        A, lda, W, ldw, M, N, K, alpha, bias, (const void*)add, (void*)C);
  };
  auto G1 = [&](const u16* A, int lda, const u16* W, int ldw, int M, int N, int K,
                float alpha, const u16* add, u16* C) {
    gemm_bf16<1><<<dim3(N / 128, (M + 127) / 128), 256, 0, stream>>>(
        A, lda, W, ldw, M, N, K, alpha, nullptr, (const void*)add, (void*)C);
  };

  // --- slices + routing-key chain + tau ---
  slice_kernel<<<(Bc * ETOKc * CROSSc + 255) / 256, 256, 0, stream>>>(E, TXTb, IPCb, FIDCb);
  ragg_kernel<<<(Bc * 2 * CROSSc + 255) / 256, 256, 0, stream>>>(E, aggr_w, aggr_b, RAGG);
  kr1_kernel<<<(16 * 1536 + 255) / 256, 256, 0, stream>>>(RAGG, kr_w1, kr_b1, KR1);
  rk_kernel<<<(16 * HIDc + 255) / 256, 256, 0, stream>>>(KR1, kr_w2, RK);
  crk_kernel<<<(16 * QRN + 255) / 256, 256, 0, stream>>>(RK, qr_w2, CRK);
  tau_kernel<<<Bc, 256, 0, stream>>>(CRK, TAU);

  // --- weight casts ---
  castW(wq, wqb, HIDc * HIDc);     castW(wo, wob, HIDc * HIDc);
  castW(wk, wkb, HIDc * CROSSc);   castW(wv, wvb, HIDc * CROSSc);
  castW(wk_ip, wkipb, HIDc * CROSSc); castW(wv_ip, wvipb, HIDc * CROSSc);
  castW(wk_fid, wkfb, HIDc * CROSSc); castW(wv_fid, wvfb, HIDc * CROSSc);
  castW(q_ld, qldb, 128 * HIDc);   castW(q_lu, qlub, HIDc * 128);
  castW(k_ld, kldb, 128 * CROSSc); castW(k_lu, klub, HIDc * 128);
  castW(v_ld, vldb, 128 * CROSSc); castW(v_lu, vlub, HIDc * 128);
  castW(o_ld, oldb, 128 * HIDc);   castW(o_lu, olub, HIDc * 128);
  cast_w1_kernel<<<(QRN * HIDc + 255) / 256, 256, 0, stream>>>(qr_w1, W1cat);

  // --- split-bf16 qr MLP -> logits (chunked over M; chunk == batch) ---
  hipMemsetAsync(LOG, 0, (size_t)Mc * 2 * 4, stream);
  hipMemsetAsync(COUNT, 0, 4, stream);
  for (int ch = 0; ch < NCHUNK; ch++) {
    castX_chunk_kernel<<<(CHUNKR * HIDc + 255) / 256, 256, 0, stream>>>(X, Xb, Xcat, ch * CHUNKR);
    gemm_qr<<<dim3(QRN / 128, CHUNKR / 128), 256, 0, stream>>>(
        Xcat, W1cat, qr_b1, CRK + (size_t)(ch * 2) * QRN, CRK + (size_t)(ch * 2 + 1) * QRN,
        LOG, ch * CHUNKR);
  }
  route_flag_kernel<<<(Mc + 255) / 256, 256, 0, stream>>>(LOG, TAU, ROUTE, FLAGS, COUNT);
  fixup_kernel<<<64, 256, 0, stream>>>(X, qr_w1, qr_b1, CRK, FLAGS, COUNT, ROUTE);

  // --- query projection + LoRA (bf16 MFMA) ---
  G1(Xb, HIDc, qldb, HIDc, Mc, 128, HIDc, 1.0f, nullptr, TMPb);
  G1(Xb, HIDc, wqb, HIDc, Mc, HIDc, HIDc, 1.0f, nullptr, Qb);
  G1(TMPb, 128, qlub, 128, Mc, HIDc, 128, 0.6f, Qb, Qb);

  // --- text K/V + LoRA ---
  const int Mt = Bc * 77;
  G0(TXTb, CROSSc, wkb, CROSSc, Mt, HIDc, CROSSc, 1.0f, nullptr, nullptr, Kb);
  G1(TXTb, CROSSc, kldb, CROSSc, Mt, 128, CROSSc, 1.0f, nullptr, TTb);
  G0(TTb, 128, klub, 128, Mt, HIDc, 128, 0.6f, nullptr, Kb, Kb);
  G0(TXTb, CROSSc, wvb, CROSSc, Mt, HIDc, CROSSc, 1.0f, nullptr, nullptr, Vb);
  G1(TXTb, CROSSc, vldb, CROSSc, Mt, 128, CROSSc, 1.0f, nullptr, TTb);
  G0(TTb, 128, vlub, 128, Mt, HIDc, 128, 0.6f, nullptr, Vb, Vb);

  // --- ip / fid K,V ---
  G0(IPCb, CROSSc, wkipb, CROSSc, Bc * 4, HIDc, CROSSc, 1.0f, nullptr, nullptr, IPK);
  G0(IPCb, CROSSc, wvipb, CROSSc, Bc * 4, HIDc, CROSSc, 1.0f, nullptr, nullptr, IPV);
  G0(FIDCb, CROSSc, wkfb, CROSSc, Bc * 32, HIDc, CROSSc, 1.0f, nullptr, nullptr, FK);
  G0(FIDCb, CROSSc, wvfb, CROSSc, Bc * 32, HIDc, CROSSc, 1.0f, nullptr, nullptr, FV);

  // --- fused triple attention (MFMA flash, 128 rows/block) ---
  attn_kernel<<<dim3(Sc / 128, HEADSc, Bc), 256, 0, stream>>>(Qb, Kb, Vb, IPK, IPV, FK, FV, ROUTE, Hb);

  // --- output projection + LoRA + bias + residual ---
  G1(Hb, HIDc, oldb, HIDc, Mc, 128, HIDc, 1.0f, nullptr, TMPo);
  G0(TMPo, 128, olub, 128, Mc, HIDc, 128, 0.6f, bo, X, out);
  G0(Hb, HIDc, wob, HIDc, Mc, HIDc, HIDc, 1.0f, nullptr, out, out);
}

// Round 5
// 3924.347 us; speedup vs baseline: 1.2720x; 1.0885x over previous
//
#include <hip/hip_runtime.h>
#include <math.h>

#define Bc 8
#define Sc 4096
#define HIDc 1280
#define CROSSc 768
#define HEADSc 20
#define HDIMc 64
#define ETOKc 113
#define Mc (Bc * Sc) /* 32768 */
#define CHUNKR 4096
#define NCHUNK 8
#define QRN 2560
#define QRK 3840
#define MAXFLAG 4096
#define NSLICE 32
#define ESLICE (QRN / NSLICE) /* 80 */

typedef unsigned short u16;
typedef __attribute__((ext_vector_type(8))) short bf16x8;
typedef __attribute__((ext_vector_type(4))) float f32x4;

__device__ __forceinline__ float b2f(u16 u) {
  union { unsigned int i; float f; } x; x.i = ((unsigned int)u) << 16; return x.f;
}
__device__ __forceinline__ u16 f2b(float f) {
  union { float f; unsigned int i; } x; x.f = f;
  unsigned int r = x.i + 0x7FFFu + ((x.i >> 16) & 1u);
  return (u16)(r >> 16);
}
__device__ __forceinline__ float gelu_exact(float x) {
  return 0.5f * x * (1.0f + erff(x * 0.70710678118654752440f));
}

// ---------------------------------------------------------------------------
// Shared GEMM building blocks: 128x128 tile, BK=64 bf16, 256 threads (4 waves
// in 2x2), each wave 4x4 grid of 16x16x32 MFMAs. A (MxK,lda) row-major, W
// (NxK,ldw) row-major (i.e. B^T). LDS tiles row-major 64 bf16/row, no padding
// (global_load_lds needs lane-contiguous LDS: base + lane*16).
// ---------------------------------------------------------------------------
__device__ __forceinline__ void stage_tiles(
    const u16* __restrict__ A, int lda, int M, int r0,
    const u16* __restrict__ W, int ldw, int N, int c0,
    int k0, u16* smA, u16* smB, int wv, int lane) {
  const int srow = lane >> 3;         // 0..7
  const int scol = (lane & 7) * 8;    // k elem offset
#pragma unroll
  for (int ci = 0; ci < 4; ci++) {
    int c = wv + ci * 4;              // chunk 0..15, wave-uniform
    int ar = r0 + c * 8 + srow; ar = ar < M ? ar : M - 1;
    const u16* ga = A + (size_t)ar * lda + k0 + scol;
    __builtin_amdgcn_global_load_lds((const __attribute__((address_space(1))) void*)ga,
                                     (__attribute__((address_space(3))) void*)(smA + c * 512), 16, 0, 0);
    int br = c0 + c * 8 + srow; br = br < N ? br : N - 1;
    const u16* gb = W + (size_t)br * ldw + k0 + scol;
    __builtin_amdgcn_global_load_lds((const __attribute__((address_space(1))) void*)gb,
                                     (__attribute__((address_space(3))) void*)(smB + c * 512), 16, 0, 0);
  }
}

__device__ __forceinline__ void mfma_tiles(const u16* smA, const u16* smB,
                                           int wr, int wc, int lane, f32x4 acc[4][4]) {
#pragma unroll
  for (int kh = 0; kh < 2; kh++) {
    const int ko = kh * 32 + (lane >> 4) * 8;  // A[m=lane&15][k=quad*8+j]
    bf16x8 af[4], bfv[4];
#pragma unroll
    for (int i = 0; i < 4; i++)
      af[i] = *(const bf16x8*)(smA + (wr * 64 + i * 16 + (lane & 15)) * 64 + ko);
#pragma unroll
    for (int j = 0; j < 4; j++)
      bfv[j] = *(const bf16x8*)(smB + (wc * 64 + j * 16 + (lane & 15)) * 64 + ko);
#pragma unroll
    for (int i = 0; i < 4; i++)
#pragma unroll
      for (int j = 0; j < 4; j++)
        acc[i][j] = __builtin_amdgcn_mfma_f32_16x16x32_bf16(af[i], bfv[j], acc[i][j], 0, 0, 0);
  }
}

// CMODE 0: fp32 out (add fp32); CMODE 1: bf16 out (add bf16).
template <int CMODE>
__global__ __launch_bounds__(256) void gemm_bf16(
    const u16* __restrict__ A, int lda, const u16* __restrict__ W, int ldw,
    int M, int N, int K, float alpha, const float* __restrict__ bias,
    const void* __restrict__ addp, void* __restrict__ Cp) {
  __shared__ __align__(16) u16 smA[128 * 64];
  __shared__ __align__(16) u16 smB[128 * 64];
  const int t = threadIdx.x, lane = t & 63, wv = t >> 6;
  const int wr = wv >> 1, wc = wv & 1;
  const int r0 = blockIdx.y * 128, c0 = blockIdx.x * 128;
  f32x4 acc[4][4] = {};
  for (int k0 = 0; k0 < K; k0 += 64) {
    stage_tiles(A, lda, M, r0, W, ldw, N, c0, k0, smA, smB, wv, lane);
    __syncthreads();
    mfma_tiles(smA, smB, wr, wc, lane, acc);
    __syncthreads();
  }
  const int cl = lane & 15, quad = lane >> 4;
#pragma unroll
  for (int i = 0; i < 4; i++) {
#pragma unroll
    for (int j = 0; j < 4; j++) {
      int gc = c0 + wc * 64 + j * 16 + cl;
      if (gc >= N) continue;
      float bv = bias ? bias[gc] : 0.0f;
#pragma unroll
      for (int r = 0; r < 4; r++) {
        int gr = r0 + wr * 64 + i * 16 + quad * 4 + r;  // D: col=lane&15, row=quad*4+reg
        if (gr >= M) continue;
        float v = alpha * acc[i][j][r] + bv;
        if (CMODE == 0) {
          const float* add = (const float*)addp;
          if (add) v += add[(size_t)gr * N + gc];
          ((float*)Cp)[(size_t)gr * N + gc] = v;
        } else {
          const u16* add = (const u16*)addp;
          if (add) v += b2f(add[(size_t)gr * N + gc]);
          ((u16*)Cp)[(size_t)gr * N + gc] = f2b(v);
        }
      }
    }
  }
}

// Split-bf16 qr GEMM (K=3840 = hi.hi + hi.lo + lo.hi) with fused
// gelu(t1+b1) . crk epilogue -> atomic partial logits. M=CHUNKR, N=QRN.
__global__ __launch_bounds__(256) void gemm_qr(
    const u16* __restrict__ A, const u16* __restrict__ W,
    const float* __restrict__ b1, const float* __restrict__ crk0,
    const float* __restrict__ crk1, float* __restrict__ LOG, int mbase) {
  __shared__ __align__(16) u16 smA[128 * 64];
  __shared__ __align__(16) u16 smB[128 * 64];
  const int t = threadIdx.x, lane = t & 63, wv = t >> 6;
  const int wr = wv >> 1, wc = wv & 1;
  const int r0 = blockIdx.y * 128, c0 = blockIdx.x * 128;
  f32x4 acc[4][4] = {};
  for (int k0 = 0; k0 < QRK; k0 += 64) {
    stage_tiles(A, QRK, CHUNKR, r0, W, QRK, QRN, c0, k0, smA, smB, wv, lane);
    __syncthreads();
    mfma_tiles(smA, smB, wr, wc, lane, acc);
    __syncthreads();
  }
  const int cl = lane & 15, quad = lane >> 4;
#pragma unroll
  for (int i = 0; i < 4; i++) {
    float p0[4] = {0.f, 0.f, 0.f, 0.f};
    float p1[4] = {0.f, 0.f, 0.f, 0.f};
#pragma unroll
    for (int j = 0; j < 4; j++) {
      int gc = c0 + wc * 64 + j * 16 + cl;
      float bv = b1[gc], c0v = crk0[gc], c1v = crk1[gc];
#pragma unroll
      for (int r = 0; r < 4; r++) {
        float g = gelu_exact(acc[i][j][r] + bv);
        p0[r] = fmaf(g, c0v, p0[r]);
        p1[r] = fmaf(g, c1v, p1[r]);
      }
    }
#pragma unroll
    for (int off = 1; off < 16; off <<= 1) {
#pragma unroll
      for (int r = 0; r < 4; r++) {
        p0[r] += __shfl_xor(p0[r], off);
        p1[r] += __shfl_xor(p1[r], off);
      }
    }
    if (cl == 0) {
#pragma unroll
      for (int r = 0; r < 4; r++) {
        int gm = mbase + r0 + wr * 64 + i * 16 + quad * 4 + r;
        atomicAdd(&LOG[2 * gm + 0], p0[r]);
        atomicAdd(&LOG[2 * gm + 1], p1[r]);
      }
    }
  }
}

// ---------------------------------------------------------------------------
// Casts
// ---------------------------------------------------------------------------
__global__ void cast_bf16_kernel(const float* __restrict__ src, u16* __restrict__ dst, int n4) {
  int i = blockIdx.x * 256 + threadIdx.x;
  if (i >= n4) return;
  float4 v = ((const float4*)src)[i];
  ushort4 o;
  o.x = f2b(v.x); o.y = f2b(v.y); o.z = f2b(v.z); o.w = f2b(v.w);
  ((ushort4*)dst)[i] = o;
}

__global__ void castX_chunk_kernel(const float* __restrict__ X, u16* __restrict__ Xb,
                                   u16* __restrict__ Xcat, int rowstart) {
  int i = blockIdx.x * 256 + threadIdx.x;
  if (i >= CHUNKR * HIDc) return;
  int r = i / HIDc, c = i % HIDc;
  float x = X[(size_t)(rowstart + r) * HIDc + c];
  u16 hi = f2b(x);
  u16 lob = f2b(x - b2f(hi));
  Xb[(size_t)(rowstart + r) * HIDc + c] = hi;
  size_t rb = (size_t)r * QRK;
  Xcat[rb + c] = hi; Xcat[rb + HIDc + c] = hi; Xcat[rb + 2 * HIDc + c] = lob;
}

__global__ void cast_w1_kernel(const float* __restrict__ w1, u16* __restrict__ W1cat) {
  int i = blockIdx.x * 256 + threadIdx.x;
  if (i >= QRN * HIDc) return;
  int r = i / HIDc, c = i % HIDc;
  float w = w1[i];
  u16 hi = f2b(w);
  u16 lob = f2b(w - b2f(hi));
  size_t rb = (size_t)r * QRK;
  W1cat[rb + c] = hi; W1cat[rb + HIDc + c] = lob; W1cat[rb + 2 * HIDc + c] = hi;
}

__global__ void slice_kernel(const float* __restrict__ E, u16* __restrict__ txt,
                             u16* __restrict__ ip, u16* __restrict__ fid) {
  int i = blockIdx.x * 256 + threadIdx.x;
  if (i >= Bc * ETOKc * CROSSc) return;
  int c = i % CROSSc;
  int rr = i / CROSSc;
  int tok = rr % ETOKc, b = rr / ETOKc;
  u16 v = f2b(E[i]);
  if (tok < 77) txt[((size_t)b * 77 + tok) * CROSSc + c] = v;
  else if (tok < 81) ip[((size_t)b * 4 + (tok - 77)) * CROSSc + c] = v;
  else fid[((size_t)b * 32 + (tok - 81)) * CROSSc + c] = v;
}

// ---------------------------------------------------------------------------
// Routing-key chain (tiny, fp32, unchanged) + tau
// ---------------------------------------------------------------------------
__global__ void ragg_kernel(const float* __restrict__ E, const float* __restrict__ aw,
                            const float* __restrict__ ab, float* __restrict__ ragg) {
  int i = blockIdx.x * 256 + threadIdx.x;
  if (i >= Bc * 2 * CROSSc) return;
  int c = i % CROSSc;
  int f = (i / CROSSc) & 1;
  int b = i / (2 * CROSSc);
  const float* base = E + ((size_t)b * ETOKc + 81 + f * 16) * CROSSc + c;
  float s = ab[0];
#pragma unroll
  for (int tk = 0; tk < 16; tk++) s = fmaf(base[tk * CROSSc], aw[tk], s);
  ragg[i] = s;
}

__global__ void kr1_kernel(const float* __restrict__ ragg, const float* __restrict__ w1,
                           const float* __restrict__ b1, float* __restrict__ kr1) {
  int i = blockIdx.x * 256 + threadIdx.x;
  if (i >= 16 * 1536) return;
  int j = i % 1536, bf = i / 1536;
  const float* a = ragg + (size_t)bf * CROSSc;
  const float* w = w1 + (size_t)j * CROSSc;
  float s = b1[j];
  for (int c = 0; c < CROSSc; c++) s = fmaf(a[c], w[c], s);
  kr1[i] = gelu_exact(s);
}

__global__ void rk_kernel(const float* __restrict__ kr1, const float* __restrict__ w2,
                          float* __restrict__ rk) {
  int i = blockIdx.x * 256 + threadIdx.x;
  if (i >= 16 * HIDc) return;
  int d = i % HIDc, bf = i / HIDc;
  const float* a = kr1 + (size_t)bf * 1536;
  const float* w = w2 + (size_t)d * 1536;
  float s = 0.f;
  for (int j = 0; j < 1536; j++) s = fmaf(a[j], w[j], s);
  rk[i] = s;
}

__global__ void crk_kernel(const float* __restrict__ rk, const float* __restrict__ qr_w2,
                           float* __restrict__ crk) {
  int i = blockIdx.x * 256 + threadIdx.x;
  if (i >= 16 * QRN) return;
  int e = i % QRN, bf = i / QRN;
  const float* r = rk + (size_t)bf * HIDc;
  float s = 0.f;
  for (int d = 0; d < HIDc; d++) s = fmaf(r[d], qr_w2[(size_t)d * QRN + e], s);
  crk[i] = s;
}

__global__ void tau_kernel(const float* __restrict__ crk, float* __restrict__ tau) {
  __shared__ float red[256];
  int t = threadIdx.x, b = blockIdx.x;
  const float* c0 = crk + (size_t)(b * 2) * QRN;
  const float* c1 = c0 + QRN;
  float s = 0.f;
  for (int e = t; e < QRN; e += 256) { float d = c0[e] - c1[e]; s = fmaf(d, d, s); }
  red[t] = s; __syncthreads();
  for (int o = 128; o; o >>= 1) { if (t < o) red[t] += red[t + o]; __syncthreads(); }
  if (t == 0) tau[b] = 1e-4f * sqrtf(red[0]);  // ~22x split-bf16 err rms
}

__global__ void route_flag_kernel(const float* __restrict__ LOG, const float* __restrict__ tau,
                                  int* __restrict__ route, int* __restrict__ flags,
                                  int* __restrict__ count) {
  int i = blockIdx.x * 256 + threadIdx.x;
  if (i >= Mc) return;
  float l0 = LOG[2 * i], l1 = LOG[2 * i + 1];
  route[i] = (l1 > l0) ? 1 : 0;
  if (fabsf(l1 - l0) < tau[i >> 12]) {
    int idx = atomicAdd(count, 1);
    if (idx < MAXFLAG) flags[idx] = i;
  }
}

// ---------------------------------------------------------------------------
// Exact fp32 recompute of routing for near-tie rows — parallel two-phase.
// Old single-kernel version: 64 blocks, per-lane-private w1 rows (uncoalesced,
// 64 cache lines per wave load) + serial fmaf chains -> 550 us at 0.15%
// VALUBusy for ~4 flagged rows. New: work item = (flag, e-slice of 80);
// wave-per-e with lanes splitting k (coalesced w1 reads, shfl_xor reduce),
// per-wave partials atomically added into FIXP[fi], then a tiny compare pass.
// ---------------------------------------------------------------------------
__global__ __launch_bounds__(256) void fixup_partial(
    const float* __restrict__ X, const float* __restrict__ w1,
    const float* __restrict__ b1, const float* __restrict__ crk,
    const int* __restrict__ flags, const int* __restrict__ count,
    float* __restrict__ fixp) {
  __shared__ float xr[HIDc];
  int n = *count; if (n > MAXFLAG) n = MAXFLAG;
  const int t = threadIdx.x, lane = t & 63, wv = t >> 6;
  for (int w = blockIdx.x; w < n * NSLICE; w += gridDim.x) {
    const int fi = w / NSLICE, sl = w % NSLICE;
    const int m = flags[fi], b = m >> 12;
    __syncthreads();
    for (int k = t; k < HIDc; k += 256) xr[k] = X[(size_t)m * HIDc + k];
    __syncthreads();
    float p0 = 0.f, p1 = 0.f;
    const int ebase = sl * ESLICE + wv * (ESLICE / 4);
#pragma unroll 4
    for (int j = 0; j < ESLICE / 4; j++) {     // 20 e's per wave
      const int e = ebase + j;
      const float* wrow = w1 + (size_t)e * HIDc;
      float s = 0.f;
      for (int k = lane; k < HIDc; k += 64) s = fmaf(xr[k], wrow[k], s);
#pragma unroll
      for (int o = 1; o < 64; o <<= 1) s += __shfl_xor(s, o);
      if (lane == 0) {
        float g = gelu_exact(s + b1[e]);
        p0 = fmaf(g, crk[(size_t)(b * 2) * QRN + e], p0);
        p1 = fmaf(g, crk[(size_t)(b * 2 + 1) * QRN + e], p1);
      }
    }
    if (lane == 0) {
      atomicAdd(&fixp[2 * fi + 0], p0);
      atomicAdd(&fixp[2 * fi + 1], p1);
    }
  }
}

__global__ void fixup_final(const float* __restrict__ fixp, const int* __restrict__ flags,
                            const int* __restrict__ count, int* __restrict__ route) {
  int n = *count; if (n > MAXFLAG) n = MAXFLAG;
  int i = blockIdx.x * 256 + threadIdx.x;
  if (i >= n) return;
  route[flags[i]] = (fixp[2 * i + 1] > fixp[2 * i]) ? 1 : 0;
}

// ---------------------------------------------------------------------------
// Fused triple attention — MFMA flash version (verified round 4: 4947->4272).
// Keys for one (b,h) padded into a 128-row tile:
//   0-76 text | 77-79 pad | 80-83 ip | 84-95 pad | 96-111 fid f0 | 112-127 fid f1
// QK^T computed SWAPPED (A=K, B=Q) -> S^T[key][qrow]; per-row softmax is a
// 4-reg reduce + shfl_xor(16,32). Face selection per-lane between mi=6/7.
// Segment coefs folded into P; pad keys P=0; single PV MFMA pass.
// K_lds XOR-swizzled (^(row&7)<<4); P/V^T rows padded to 136 u16.
// ---------------------------------------------------------------------------
__global__ __launch_bounds__(256) void attn_kernel(
    const u16* __restrict__ Q, const float* __restrict__ Kb,
    const float* __restrict__ Vb, const float* __restrict__ IPK,
    const float* __restrict__ IPV, const float* __restrict__ FK,
    const float* __restrict__ FV, const int* __restrict__ route,
    u16* __restrict__ H) {
  __shared__ __align__(16) u16 K_lds[128 * 64];       // swizzled, 16KB
  __shared__ __align__(16) u16 V_t[64 * 136];         // V^T [dim][key], 17.4KB
  __shared__ __align__(16) u16 P_lds[4 * 32 * 136];   // per-wave P, 34.8KB
  const int t = threadIdx.x, lane = t & 63, wv = t >> 6;
  const int cl = lane & 15, quad = lane >> 4, qr4 = quad * 4;
  const int b = blockIdx.z, hh = blockIdx.y;
  const int s0 = blockIdx.x * 128;

  // ---- stage K (bf16, swizzled) ----
  for (int idx = t; idx < 128 * 16; idx += 256) {
    const int row = idx >> 4, c4 = idx & 15;
    float4 v = make_float4(0.f, 0.f, 0.f, 0.f);
    const float* src = nullptr;
    if (row < 77)                    src = Kb  + ((size_t)(b * 77 + row)) * HIDc;
    else if (row >= 80 && row < 84)  src = IPK + ((size_t)(b * 4 + row - 80)) * HIDc;
    else if (row >= 96)              src = FK  + ((size_t)(b * 32 + row - 96)) * HIDc;
    if (src) v = ((const float4*)(src + hh * HDIMc))[c4];
    unsigned int w0 = ((unsigned int)f2b(v.y) << 16) | f2b(v.x);
    unsigned int w1 = ((unsigned int)f2b(v.w) << 16) | f2b(v.z);
    int byte = (row * 128 + c4 * 8) ^ ((row & 7) << 4);
    *(uint2*)((char*)K_lds + byte) = make_uint2(w0, w1);
  }
  // ---- stage V^T (pad keys written as zero: P=0 * garbage could be NaN) ----
  for (int idx = t; idx < 128 * 16; idx += 256) {
    const int row = idx >> 4, c4 = idx & 15;
    float4 v = make_float4(0.f, 0.f, 0.f, 0.f);
    const float* src = nullptr;
    if (row < 77)                    src = Vb  + ((size_t)(b * 77 + row)) * HIDc;
    else if (row >= 80 && row < 84)  src = IPV + ((size_t)(b * 4 + row - 80)) * HIDc;
    else if (row >= 96)              src = FV  + ((size_t)(b * 32 + row - 96)) * HIDc;
    if (src) v = ((const float4*)(src + hh * HDIMc))[c4];
    V_t[(c4 * 4 + 0) * 136 + row] = f2b(v.x);
    V_t[(c4 * 4 + 1) * 136 + row] = f2b(v.y);
    V_t[(c4 * 4 + 2) * 136 + row] = f2b(v.z);
    V_t[(c4 * 4 + 3) * 136 + row] = f2b(v.w);
  }
  __syncthreads();

  const size_t mbase = (size_t)b * Sc + s0 + wv * 32;
  // Q fragments straight from global (B-operand: n=lane&15 -> qrow, k=quad*8)
  bf16x8 qf[2][2];
#pragma unroll
  for (int ni = 0; ni < 2; ni++)
#pragma unroll
    for (int kk = 0; kk < 2; kk++)
      qf[ni][kk] = *(const bf16x8*)(Q + (mbase + ni * 16 + cl) * HIDc + hh * HDIMc + kk * 32 + quad * 8);
  const int face[2] = { route[mbase + cl], route[mbase + 16 + cl] };

  // ---- QK^T (swapped): acc[mi][ni] = S^T[key=mi*16+qr4+r][qrow=ni*16+cl] ----
  f32x4 acc[8][2] = {};
#pragma unroll
  for (int kk = 0; kk < 2; kk++) {
    bf16x8 af[8];
#pragma unroll
    for (int mi = 0; mi < 8; mi++) {
      const int row = mi * 16 + cl;
      const int byte = (row * 128 + (kk * 32 + quad * 8) * 2) ^ ((row & 7) << 4);
      af[mi] = *(const bf16x8*)((const char*)K_lds + byte);
    }
#pragma unroll
    for (int mi = 0; mi < 8; mi++)
#pragma unroll
      for (int ni = 0; ni < 2; ni++)
        acc[mi][ni] = __builtin_amdgcn_mfma_f32_16x16x32_bf16(af[mi], qf[ni][kk], acc[mi][ni], 0, 0, 0);
  }

  // ---- per-row softmax (3 segments) + P (coef/l folded in) -> LDS ----
  u16* Pw = P_lds + wv * 32 * 136;
  const float NEG = -1e30f;
#pragma unroll
  for (int ni = 0; ni < 2; ni++) {
    float e[8][4];
#pragma unroll
    for (int mi = 0; mi < 8; mi++)
#pragma unroll
      for (int r = 0; r < 4; r++) e[mi][r] = 0.125f * acc[mi][ni][r];
    // masks: mi4 keys 64..79 valid <=76; mi5 keys 80..95 valid quad==0
#pragma unroll
    for (int r = 0; r < 4; r++) {
      e[4][r] = (qr4 + r <= 12) ? e[4][r] : NEG;
      e[5][r] = (quad == 0) ? e[5][r] : NEG;
    }
    // text: mi 0..4
    float mt = NEG;
#pragma unroll
    for (int mi = 0; mi < 5; mi++)
#pragma unroll
      for (int r = 0; r < 4; r++) mt = fmaxf(mt, e[mi][r]);
    mt = fmaxf(mt, __shfl_xor(mt, 16));
    mt = fmaxf(mt, __shfl_xor(mt, 32));
    float lt = 0.f;
#pragma unroll
    for (int mi = 0; mi < 5; mi++)
#pragma unroll
      for (int r = 0; r < 4; r++) { e[mi][r] = __expf(e[mi][r] - mt); lt += e[mi][r]; }
    lt += __shfl_xor(lt, 16); lt += __shfl_xor(lt, 32);
    // ip: mi 5
    float mp = NEG;
#pragma unroll
    for (int r = 0; r < 4; r++) mp = fmaxf(mp, e[5][r]);
    mp = fmaxf(mp, __shfl_xor(mp, 16));
    mp = fmaxf(mp, __shfl_xor(mp, 32));
    float lp = 0.f;
#pragma unroll
    for (int r = 0; r < 4; r++) { e[5][r] = __expf(e[5][r] - mp); lp += e[5][r]; }
    lp += __shfl_xor(lp, 16); lp += __shfl_xor(lp, 32);
    // fid: per-lane face selects mi6 (f0) or mi7 (f1)
    const int f = face[ni];
    float sf[4];
#pragma unroll
    for (int r = 0; r < 4; r++) sf[r] = f ? e[7][r] : e[6][r];
    float mf = NEG;
#pragma unroll
    for (int r = 0; r < 4; r++) mf = fmaxf(mf, sf[r]);
    mf = fmaxf(mf, __shfl_xor(mf, 16));
    mf = fmaxf(mf, __shfl_xor(mf, 32));
    float lf = 0.f;
#pragma unroll
    for (int r = 0; r < 4; r++) { sf[r] = __expf(sf[r] - mf); lf += sf[r]; }
    lf += __shfl_xor(lf, 16); lf += __shfl_xor(lf, 32);
    const float sct = 1.0f / lt, sci = 0.6f / lp, scf = 0.7f / lf;
#pragma unroll
    for (int mi = 0; mi < 5; mi++)
#pragma unroll
      for (int r = 0; r < 4; r++) e[mi][r] *= sct;
#pragma unroll
    for (int r = 0; r < 4; r++) {
      e[5][r] *= sci;
      const float pf = sf[r] * scf;
      e[6][r] = f ? 0.f : pf;
      e[7][r] = f ? pf : 0.f;
    }
    // pack (round-to-nearest bf16) + write 4 keys (8B) per mi
    u16* prow = Pw + (ni * 16 + cl) * 136 + qr4;
#pragma unroll
    for (int mi = 0; mi < 8; mi++) {
      unsigned int a0 = (unsigned int)f2b(e[mi][0]) | ((unsigned int)f2b(e[mi][1]) << 16);
      unsigned int a1 = (unsigned int)f2b(e[mi][2]) | ((unsigned int)f2b(e[mi][3]) << 16);
      *(uint2*)(prow + mi * 16) = make_uint2(a0, a1);
    }
  }

  // ---- PV: out[qrow][dim] = P[qrow][k] * V[k][dim] over all 128 keys ----
  f32x4 pacc[2][4] = {};
#pragma unroll
  for (int kk = 0; kk < 4; kk++) {
    bf16x8 pa[2], vb[4];
#pragma unroll
    for (int mi2 = 0; mi2 < 2; mi2++)
      pa[mi2] = *(const bf16x8*)(Pw + (mi2 * 16 + cl) * 136 + kk * 32 + quad * 8);
#pragma unroll
    for (int ni2 = 0; ni2 < 4; ni2++)
      vb[ni2] = *(const bf16x8*)(V_t + (ni2 * 16 + cl) * 136 + kk * 32 + quad * 8);
#pragma unroll
    for (int mi2 = 0; mi2 < 2; mi2++)
#pragma unroll
      for (int ni2 = 0; ni2 < 4; ni2++)
        pacc[mi2][ni2] = __builtin_amdgcn_mfma_f32_16x16x32_bf16(pa[mi2], vb[ni2], pacc[mi2][ni2], 0, 0, 0);
  }
  // store: D col=lane&15 -> dim, row=quad*4+r -> qrow
#pragma unroll
  for (int mi2 = 0; mi2 < 2; mi2++) {
#pragma unroll
    for (int r = 0; r < 4; r++) {
      u16* hp = H + (mbase + mi2 * 16 + qr4 + r) * HIDc + hh * HDIMc + cl;
#pragma unroll
      for (int ni2 = 0; ni2 < 4; ni2++)
        hp[ni2 * 16] = f2b(pacc[mi2][ni2][r]);
    }
  }
}

// ---------------------------------------------------------------------------
extern "C" void kernel_launch(void* const* d_in, const int* in_sizes, int n_in,
                              void* d_out, int out_size, void* d_ws, size_t ws_size,
                              hipStream_t stream) {
  (void)in_sizes; (void)n_in; (void)out_size; (void)ws_size;
  const float* X      = (const float*)d_in[0];
  const float* E      = (const float*)d_in[1];
  const float* wq     = (const float*)d_in[2];
  const float* wk     = (const float*)d_in[3];
  const float* wv     = (const float*)d_in[4];
  const float* wo     = (const float*)d_in[5];
  const float* bo     = (const float*)d_in[6];
  const float* q_ld   = (const float*)d_in[7];
  const float* q_lu   = (const float*)d_in[8];
  const float* k_ld   = (const float*)d_in[9];
  const float* k_lu   = (const float*)d_in[10];
  const float* v_ld   = (const float*)d_in[11];
  const float* v_lu   = (const float*)d_in[12];
  const float* o_ld   = (const float*)d_in[13];
  const float* o_lu   = (const float*)d_in[14];
  const float* wk_ip  = (const float*)d_in[15];
  const float* wv_ip  = (const float*)d_in[16];
  const float* wk_fid = (const float*)d_in[17];
  const float* wv_fid = (const float*)d_in[18];
  const float* qr_w1  = (const float*)d_in[19];
  const float* qr_b1  = (const float*)d_in[20];
  const float* qr_w2  = (const float*)d_in[21];
  const float* kr_w1  = (const float*)d_in[22];
  const float* kr_b1  = (const float*)d_in[23];
  const float* kr_w2  = (const float*)d_in[24];
  const float* aggr_w = (const float*)d_in[25];
  const float* aggr_b = (const float*)d_in[26];
  float* out = (float*)d_out;

  char* base = (char*)d_ws;
  size_t off = 0;
  auto alloc = [&](size_t bytes) -> void* {
    off = (off + 255) & ~(size_t)255;
    void* p = base + off; off += bytes; return p;
  };
  u16* Xb    = (u16*)alloc((size_t)Mc * HIDc * 2);
  u16* Xcat  = (u16*)alloc((size_t)CHUNKR * QRK * 2);
  u16* W1cat = (u16*)alloc((size_t)QRN * QRK * 2);
  u16* Qb    = (u16*)alloc((size_t)Mc * HIDc * 2);
  u16* Hb    = (u16*)alloc((size_t)Mc * HIDc * 2);
  u16* TMPb  = (u16*)alloc((size_t)Mc * 128 * 2);
  u16* TMPo  = (u16*)alloc((size_t)Mc * 128 * 2);
  float* Kb  = (float*)alloc((size_t)Bc * 77 * HIDc * 4);
  float* Vb  = (float*)alloc((size_t)Bc * 77 * HIDc * 4);
  float* IPK = (float*)alloc((size_t)Bc * 4 * HIDc * 4);
  float* IPV = (float*)alloc((size_t)Bc * 4 * HIDc * 4);
  float* FK  = (float*)alloc((size_t)Bc * 32 * HIDc * 4);
  float* FV  = (float*)alloc((size_t)Bc * 32 * HIDc * 4);
  u16* TXTb  = (u16*)alloc((size_t)Bc * 77 * CROSSc * 2);
  u16* IPCb  = (u16*)alloc((size_t)Bc * 4 * CROSSc * 2);
  u16* FIDCb = (u16*)alloc((size_t)Bc * 32 * CROSSc * 2);
  u16* TTb   = (u16*)alloc((size_t)Bc * 77 * 128 * 2);
  u16* wqb   = (u16*)alloc((size_t)HIDc * HIDc * 2);
  u16* wob   = (u16*)alloc((size_t)HIDc * HIDc * 2);
  u16* wkb   = (u16*)alloc((size_t)HIDc * CROSSc * 2);
  u16* wvb   = (u16*)alloc((size_t)HIDc * CROSSc * 2);
  u16* wkipb = (u16*)alloc((size_t)HIDc * CROSSc * 2);
  u16* wvipb = (u16*)alloc((size_t)HIDc * CROSSc * 2);
  u16* wkfb  = (u16*)alloc((size_t)HIDc * CROSSc * 2);
  u16* wvfb  = (u16*)alloc((size_t)HIDc * CROSSc * 2);
  u16* qldb  = (u16*)alloc((size_t)128 * HIDc * 2);
  u16* qlub  = (u16*)alloc((size_t)HIDc * 128 * 2);
  u16* kldb  = (u16*)alloc((size_t)128 * CROSSc * 2);
  u16* klub  = (u16*)alloc((size_t)HIDc * 128 * 2);
  u16* vldb  = (u16*)alloc((size_t)128 * CROSSc * 2);
  u16* vlub  = (u16*)alloc((size_t)HIDc * 128 * 2);
  u16* oldb  = (u16*)alloc((size_t)128 * HIDc * 2);
  u16* olub  = (u16*)alloc((size_t)HIDc * 128 * 2);
  float* RAGG = (float*)alloc(16 * CROSSc * 4);
  float* KR1  = (float*)alloc(16 * 1536 * 4);
  float* RK   = (float*)alloc(16 * HIDc * 4);
  float* CRK  = (float*)alloc(16 * QRN * 4);
  float* TAU  = (float*)alloc(Bc * 4);
  float* LOG  = (float*)alloc((size_t)Mc * 2 * 4);
  int* ROUTE  = (int*)alloc((size_t)Mc * 4);
  int* FLAGS  = (int*)alloc(MAXFLAG * 4);
  int* COUNT  = (int*)alloc(4);
  float* FIXP = (float*)alloc((size_t)MAXFLAG * 2 * 4);

  auto castW = [&](const float* s, u16* d, int n) {
    cast_bf16_kernel<<<(n / 4 + 255) / 256, 256, 0, stream>>>(s, d, n / 4);
  };
  auto G0 = [&](const u16* A, int lda, const u16* W, int ldw, int M, int N, int K,
                float alpha, const float* bias, const float* add, float* C) {
    gemm_bf16<0><<<dim3(N / 128, (M + 127) / 128), 256, 0, stream>>>(
        A, lda, W, ldw, M, N, K, alpha, bias, (const void*)add, (void*)C);
  };
  auto G1 = [&](const u16* A, int lda, const u16* W, int ldw, int M, int N, int K,
                float alpha, const u16* add, u16* C) {
    gemm_bf16<1><<<dim3(N / 128, (M + 127) / 128), 256, 0, stream>>>(
        A, lda, W, ldw, M, N, K, alpha, nullptr, (const void*)add, (void*)C);
  };

  // --- slices + routing-key chain + tau ---
  slice_kernel<<<(Bc * ETOKc * CROSSc + 255) / 256, 256, 0, stream>>>(E, TXTb, IPCb, FIDCb);
  ragg_kernel<<<(Bc * 2 * CROSSc + 255) / 256, 256, 0, stream>>>(E, aggr_w, aggr_b, RAGG);
  kr1_kernel<<<(16 * 1536 + 255) / 256, 256, 0, stream>>>(RAGG, kr_w1, kr_b1, KR1);
  rk_kernel<<<(16 * HIDc + 255) / 256, 256, 0, stream>>>(KR1, kr_w2, RK);
  crk_kernel<<<(16 * QRN + 255) / 256, 256, 0, stream>>>(RK, qr_w2, CRK);
  tau_kernel<<<Bc, 256, 0, stream>>>(CRK, TAU);

  // --- weight casts ---
  castW(wq, wqb, HIDc * HIDc);     castW(wo, wob, HIDc * HIDc);
  castW(wk, wkb, HIDc * CROSSc);   castW(wv, wvb, HIDc * CROSSc);
  castW(wk_ip, wkipb, HIDc * CROSSc); castW(wv_ip, wvipb, HIDc * CROSSc);
  castW(wk_fid, wkfb, HIDc * CROSSc); castW(wv_fid, wvfb, HIDc * CROSSc);
  castW(q_ld, qldb, 128 * HIDc);   castW(q_lu, qlub, HIDc * 128);
  castW(k_ld, kldb, 128 * CROSSc); castW(k_lu, klub, HIDc * 128);
  castW(v_ld, vldb, 128 * CROSSc); castW(v_lu, vlub, HIDc * 128);
  castW(o_ld, oldb, 128 * HIDc);   castW(o_lu, olub, HIDc * 128);
  cast_w1_kernel<<<(QRN * HIDc + 255) / 256, 256, 0, stream>>>(qr_w1, W1cat);

  // --- split-bf16 qr MLP -> logits (chunked over M; chunk == batch) ---
  hipMemsetAsync(LOG, 0, (size_t)Mc * 2 * 4, stream);
  hipMemsetAsync(COUNT, 0, 4, stream);
  hipMemsetAsync(FIXP, 0, (size_t)MAXFLAG * 2 * 4, stream);
  for (int ch = 0; ch < NCHUNK; ch++) {
    castX_chunk_kernel<<<(CHUNKR * HIDc + 255) / 256, 256, 0, stream>>>(X, Xb, Xcat, ch * CHUNKR);
    gemm_qr<<<dim3(QRN / 128, CHUNKR / 128), 256, 0, stream>>>(
        Xcat, W1cat, qr_b1, CRK + (size_t)(ch * 2) * QRN, CRK + (size_t)(ch * 2 + 1) * QRN,
        LOG, ch * CHUNKR);
  }
  route_flag_kernel<<<(Mc + 255) / 256, 256, 0, stream>>>(LOG, TAU, ROUTE, FLAGS, COUNT);
  fixup_partial<<<2048, 256, 0, stream>>>(X, qr_w1, qr_b1, CRK, FLAGS, COUNT, FIXP);
  fixup_final<<<MAXFLAG / 256, 256, 0, stream>>>(FIXP, FLAGS, COUNT, ROUTE);

  // --- query projection + LoRA (bf16 MFMA) ---
  G1(Xb, HIDc, qldb, HIDc, Mc, 128, HIDc, 1.0f, nullptr, TMPb);
  G1(Xb, HIDc, wqb, HIDc, Mc, HIDc, HIDc, 1.0f, nullptr, Qb);
  G1(TMPb, 128, qlub, 128, Mc, HIDc, 128, 0.6f, Qb, Qb);

  // --- text K/V + LoRA ---
  const int Mt = Bc * 77;
  G0(TXTb, CROSSc, wkb, CROSSc, Mt, HIDc, CROSSc, 1.0f, nullptr, nullptr, Kb);
  G1(TXTb, CROSSc, kldb, CROSSc, Mt, 128, CROSSc, 1.0f, nullptr, TTb);
  G0(TTb, 128, klub, 128, Mt, HIDc, 128, 0.6f, nullptr, Kb, Kb);
  G0(TXTb, CROSSc, wvb, CROSSc, Mt, HIDc, CROSSc, 1.0f, nullptr, nullptr, Vb);
  G1(TXTb, CROSSc, vldb, CROSSc, Mt, 128, CROSSc, 1.0f, nullptr, TTb);
  G0(TTb, 128, vlub, 128, Mt, HIDc, 128, 0.6f, nullptr, Vb, Vb);

  // --- ip / fid K,V ---
  G0(IPCb, CROSSc, wkipb, CROSSc, Bc * 4, HIDc, CROSSc, 1.0f, nullptr, nullptr, IPK);
  G0(IPCb, CROSSc, wvipb, CROSSc, Bc * 4, HIDc, CROSSc, 1.0f, nullptr, nullptr, IPV);
  G0(FIDCb, CROSSc, wkfb, CROSSc, Bc * 32, HIDc, CROSSc, 1.0f, nullptr, nullptr, FK);
  G0(FIDCb, CROSSc, wvfb, CROSSc, Bc * 32, HIDc, CROSSc, 1.0f, nullptr, nullptr, FV);

  // --- fused triple attention (MFMA flash, 128 rows/block) ---
  attn_kernel<<<dim3(Sc / 128, HEADSc, Bc), 256, 0, stream>>>(Qb, Kb, Vb, IPK, IPV, FK, FV, ROUTE, Hb);

  // --- output projection + LoRA + bias + residual ---
  G1(Hb, HIDc, oldb, HIDc, Mc, 128, HIDc, 1.0f, nullptr, TMPo);
  G0(TMPo, 128, olub, 128, Mc, HIDc, 128, 0.6f, bo, X, out);
  G0(Hb, HIDc, wob, HIDc, Mc, HIDc, HIDc, 1.0f, nullptr, out, out);
}